// Round 3
// baseline (986.576 us; speedup 1.0000x reference)
//
#include <hip/hip_runtime.h>

#define BN_EPS 1e-5f
#define TN 128       // nodes per fused-layer block
#define SCAN_BS 1024 // elements per scan block (256 thr x 4)

static __device__ __forceinline__ unsigned short f2bf(float f) {
    unsigned u = __float_as_uint(f);
    u += 0x7fff + ((u >> 16) & 1);   // round-to-nearest-even
    return (unsigned short)(u >> 16);
}
static __device__ __forceinline__ float bf2f(unsigned short s) {
    return __uint_as_float(((unsigned)s) << 16);
}

// ============ CSR build ============
__global__ __launch_bounds__(256) void deg_kernel(
    const int* __restrict__ dst, int* __restrict__ deg, int E)
{
    int e = blockIdx.x * 256 + threadIdx.x;
    if (e < E) atomicAdd(&deg[dst[e]], 1);
}

__global__ __launch_bounds__(256) void scan_part_kernel(
    const int* __restrict__ deg, int* __restrict__ rowstart,
    int* __restrict__ blocksum, int nN)
{
    __shared__ int lsum[256];
    const int t = threadIdx.x;
    const int base = blockIdx.x * SCAN_BS + t * 4;
    int v[4]; int s = 0;
#pragma unroll
    for (int k = 0; k < 4; ++k) {
        const int idx = base + k;
        v[k] = (idx < nN) ? deg[idx] : 0;
        s += v[k];
    }
    lsum[t] = s;
    __syncthreads();
    for (int off = 1; off < 256; off <<= 1) {
        const int x = lsum[t];
        const int y = (t >= off) ? lsum[t - off] : 0;
        __syncthreads();
        lsum[t] = x + y;
        __syncthreads();
    }
    int run = lsum[t] - s;
#pragma unroll
    for (int k = 0; k < 4; ++k) {
        const int idx = base + k;
        if (idx < nN) rowstart[idx] = run;
        run += v[k];
    }
    if (t == 255) blocksum[blockIdx.x] = lsum[255];
}

__global__ void scan_top_kernel(int* __restrict__ blocksum,
                                int* __restrict__ blockoff, int nblk)
{
    if (threadIdx.x == 0 && blockIdx.x == 0) {
        int run = 0;
        for (int i = 0; i < nblk; ++i) { blockoff[i] = run; run += blocksum[i]; }
    }
}

__global__ __launch_bounds__(256) void scan_add_kernel(
    int* __restrict__ rowstart, int* __restrict__ cursor,
    const int* __restrict__ blockoff, int nN)
{
    const int i = blockIdx.x * 256 + threadIdx.x;
    if (i < nN) {
        const int r = rowstart[i] + blockoff[i / SCAN_BS];
        rowstart[i] = r;
        cursor[i] = r;
    }
}

__global__ __launch_bounds__(256) void fill_kernel(
    const int* __restrict__ src, const int* __restrict__ dst,
    int* __restrict__ cursor, int* __restrict__ eidx, int E)
{
    const int e = blockIdx.x * 256 + threadIdx.x;
    if (e < E) {
        const int p = atomicAdd(&cursor[dst[e]], 1);
        eidx[p] = src[e];
    }
}

__global__ __launch_bounds__(256) void cnt_kernel(
    const int* __restrict__ batch, int* __restrict__ cnt, int nN)
{
    const int n = blockIdx.x * 256 + threadIdx.x;
    if (n < nN) atomicAdd(&cnt[batch[n]], 1);
}

// ============ fused layer: gather(+prev-BN affine) -> MLP -> z(bf16) + BN stats + pool(z) ====
__global__ __launch_bounds__(256) void gin_layer_kernel(
    const float* __restrict__ x0,               // layer-0 input (f32), null for l>0
    const unsigned short* __restrict__ zprev,   // bf16 z of prev layer, null for l==0
    const float* __restrict__ bnprev,           // bnstats of prev layer (128), null for l==0
    const float* __restrict__ gamma, const float* __restrict__ beta,
    const int* __restrict__ rowstart, const int* __restrict__ deg,
    const int* __restrict__ eidx, const int* __restrict__ batch,
    const float* __restrict__ w1, const float* __restrict__ b1,
    const float* __restrict__ w2, const float* __restrict__ b2,
    unsigned short* __restrict__ zout, float* __restrict__ bnstats,
    float* __restrict__ xpz, int layer, int nN, float invN)
{
    __shared__ float sA[64 * 132];     // A tile (feat-major, padded) / T tile
    __shared__ float sW[64 * 64];      // W1 then W2 (time-shared)
    __shared__ float sB1[64], sB2[64], sSum[64], sSq[64];
    __shared__ float sPool[4 * 64];
    __shared__ int sGfirst;
    const int tid = threadIdx.x;
    const int n0 = blockIdx.x * TN;
    const int lane = tid & 63;

    // start W1 load early
    const float4* w1v = reinterpret_cast<const float4*>(w1 + (size_t)layer * 4096);
    float4* sWv = reinterpret_cast<float4*>(sW);
    for (int i = tid; i < 1024; i += 256) sWv[i] = w1v[i];
    if (tid < 64) {
        sB1[tid] = b1[layer * 64 + tid];
        sB2[tid] = b2[layer * 64 + tid];
        sSum[tid] = 0.f; sSq[tid] = 0.f;
    }
    sPool[tid] = 0.f;
    if (tid == 0) sGfirst = batch[n0];

    // previous layer's folded BN affine (per feature = lane)
    float sc = 1.f, sh = 0.f;
    if (bnprev) {
        const float mean = bnprev[lane] * invN;
        const float var  = fmaxf(bnprev[64 + lane] * invN - mean * mean, 0.f);
        const float g  = gamma[(layer - 1) * 64 + lane];
        const float bt = beta[(layer - 1) * 64 + lane];
        sc = g * rsqrtf(var + BN_EPS);
        sh = bt - mean * sc;
    }

    // gather: wave wv handles nodes n0+wv*32 .. +31; lane = feature
    const int wv = tid >> 6;
    if (zprev) {
        for (int t = 0; t < 32; ++t) {
            const int node = n0 + wv * 32 + t;
            if (node >= nN) break;
            const int rs = rowstart[node];
            const int dgr = deg[node];
            float acc = bf2f(zprev[(size_t)node * 64 + lane]);
            int i = 0;
            for (; i + 8 <= dgr; i += 8) {
                const int s0 = eidx[rs+i+0], s1 = eidx[rs+i+1], s2 = eidx[rs+i+2], s3 = eidx[rs+i+3];
                const int s4 = eidx[rs+i+4], s5 = eidx[rs+i+5], s6 = eidx[rs+i+6], s7 = eidx[rs+i+7];
                const float v0 = bf2f(zprev[(size_t)s0*64 + lane]);
                const float v1 = bf2f(zprev[(size_t)s1*64 + lane]);
                const float v2 = bf2f(zprev[(size_t)s2*64 + lane]);
                const float v3 = bf2f(zprev[(size_t)s3*64 + lane]);
                const float v4 = bf2f(zprev[(size_t)s4*64 + lane]);
                const float v5 = bf2f(zprev[(size_t)s5*64 + lane]);
                const float v6 = bf2f(zprev[(size_t)s6*64 + lane]);
                const float v7 = bf2f(zprev[(size_t)s7*64 + lane]);
                acc += ((v0 + v1) + (v2 + v3)) + ((v4 + v5) + (v6 + v7));
            }
            for (; i < dgr; ++i) acc += bf2f(zprev[(size_t)eidx[rs + i] * 64 + lane]);
            acc = fmaf(acc, sc, (float)(dgr + 1) * sh);
            sA[lane * 132 + wv * 32 + t] = acc;
        }
    } else {
        for (int t = 0; t < 32; ++t) {
            const int node = n0 + wv * 32 + t;
            if (node >= nN) break;
            const int rs = rowstart[node];
            const int dgr = deg[node];
            float acc = x0[(size_t)node * 64 + lane];
            int i = 0;
            for (; i + 8 <= dgr; i += 8) {
                const int s0 = eidx[rs+i+0], s1 = eidx[rs+i+1], s2 = eidx[rs+i+2], s3 = eidx[rs+i+3];
                const int s4 = eidx[rs+i+4], s5 = eidx[rs+i+5], s6 = eidx[rs+i+6], s7 = eidx[rs+i+7];
                const float v0 = x0[(size_t)s0*64 + lane];
                const float v1 = x0[(size_t)s1*64 + lane];
                const float v2 = x0[(size_t)s2*64 + lane];
                const float v3 = x0[(size_t)s3*64 + lane];
                const float v4 = x0[(size_t)s4*64 + lane];
                const float v5 = x0[(size_t)s5*64 + lane];
                const float v6 = x0[(size_t)s6*64 + lane];
                const float v7 = x0[(size_t)s7*64 + lane];
                acc += ((v0 + v1) + (v2 + v3)) + ((v4 + v5) + (v6 + v7));
            }
            for (; i < dgr; ++i) acc += x0[(size_t)eidx[rs + i] * 64 + lane];
            sA[lane * 132 + wv * 32 + t] = acc;  // sc=1, sh=0
        }
    }
    __syncthreads();   // A tile + W1 ready

    const int jq = tid & 15;
    const int no = tid >> 4;
    float acc[8][4];

    // ---- mm1: T = relu(A @ W1 + b1) ----
#pragma unroll
    for (int nn = 0; nn < 8; ++nn)
#pragma unroll
        for (int jj = 0; jj < 4; ++jj) acc[nn][jj] = sB1[jq * 4 + jj];
#pragma unroll 4
    for (int k = 0; k < 64; ++k) {
        const float4 a0 = *reinterpret_cast<const float4*>(&sA[k * 132 + no * 8]);
        const float4 a1 = *reinterpret_cast<const float4*>(&sA[k * 132 + no * 8 + 4]);
        const float4 wv4 = *reinterpret_cast<const float4*>(&sW[k * 64 + jq * 4]);
        const float av[8] = {a0.x, a0.y, a0.z, a0.w, a1.x, a1.y, a1.z, a1.w};
        const float wj[4] = {wv4.x, wv4.y, wv4.z, wv4.w};
#pragma unroll
        for (int nn = 0; nn < 8; ++nn)
#pragma unroll
            for (int jj = 0; jj < 4; ++jj) acc[nn][jj] = fmaf(av[nn], wj[jj], acc[nn][jj]);
    }
    __syncthreads();   // done reading A + W1

    // write T (relu) into sA, and load W2 into sW
#pragma unroll
    for (int nn = 0; nn < 8; ++nn)
#pragma unroll
        for (int jj = 0; jj < 4; ++jj)
            sA[(jq * 4 + jj) * 132 + no * 8 + nn] = fmaxf(acc[nn][jj], 0.f);
    const float4* w2v = reinterpret_cast<const float4*>(w2 + (size_t)layer * 4096);
    for (int i = tid; i < 1024; i += 256) sWv[i] = w2v[i];
    __syncthreads();

    // ---- mm2: Z = relu(T @ W2 + b2) ----
#pragma unroll
    for (int nn = 0; nn < 8; ++nn)
#pragma unroll
        for (int jj = 0; jj < 4; ++jj) acc[nn][jj] = sB2[jq * 4 + jj];
#pragma unroll 4
    for (int k = 0; k < 64; ++k) {
        const float4 a0 = *reinterpret_cast<const float4*>(&sA[k * 132 + no * 8]);
        const float4 a1 = *reinterpret_cast<const float4*>(&sA[k * 132 + no * 8 + 4]);
        const float4 wv4 = *reinterpret_cast<const float4*>(&sW[k * 64 + jq * 4]);
        const float av[8] = {a0.x, a0.y, a0.z, a0.w, a1.x, a1.y, a1.z, a1.w};
        const float wj[4] = {wv4.x, wv4.y, wv4.z, wv4.w};
#pragma unroll
        for (int nn = 0; nn < 8; ++nn)
#pragma unroll
            for (int jj = 0; jj < 4; ++jj) acc[nn][jj] = fmaf(av[nn], wj[jj], acc[nn][jj]);
    }

    // ---- epilogue: relu, z store (bf16), BN partials, run-length pool ----
#pragma unroll
    for (int nn = 0; nn < 8; ++nn) {
        const int node = n0 + no * 8 + nn;
#pragma unroll
        for (int jj = 0; jj < 4; ++jj) acc[nn][jj] = fmaxf(acc[nn][jj], 0.f);
        if (node < nN) {
            ushort4 o;
            o.x = f2bf(acc[nn][0]); o.y = f2bf(acc[nn][1]);
            o.z = f2bf(acc[nn][2]); o.w = f2bf(acc[nn][3]);
            *reinterpret_cast<ushort4*>(zout + (size_t)node * 64 + jq * 4) = o;
        }
    }
#pragma unroll
    for (int jj = 0; jj < 4; ++jj) {
        float s = 0.f, q = 0.f;
#pragma unroll
        for (int nn = 0; nn < 8; ++nn) {
            const int node = n0 + no * 8 + nn;
            if (node < nN) { const float v = acc[nn][jj]; s += v; q += v * v; }
        }
        atomicAdd(&sSum[jq * 4 + jj], s);
        atomicAdd(&sSq[jq * 4 + jj], q);
    }
    // per-thread run-length pooling over its 8 consecutive nodes
    {
        int curg = -1;
        float ps[4] = {0.f, 0.f, 0.f, 0.f};
        const int gfirst = sGfirst;
#pragma unroll
        for (int nn = 0; nn < 8; ++nn) {
            const int node = n0 + no * 8 + nn;
            if (node < nN) {
                const int g = batch[node];
                if (g != curg) {
                    if (curg >= 0) {
                        const int lg = curg - gfirst;
                        if (lg < 4) {
#pragma unroll
                            for (int jj = 0; jj < 4; ++jj)
                                atomicAdd(&sPool[lg * 64 + jq * 4 + jj], ps[jj]);
                        } else {
#pragma unroll
                            for (int jj = 0; jj < 4; ++jj)
                                atomicAdd(&xpz[(size_t)curg * 64 + jq * 4 + jj], ps[jj]);
                        }
                    }
                    curg = g;
                    ps[0] = ps[1] = ps[2] = ps[3] = 0.f;
                }
#pragma unroll
                for (int jj = 0; jj < 4; ++jj) ps[jj] += acc[nn][jj];
            }
        }
        if (curg >= 0) {
            const int lg = curg - gfirst;
            if (lg < 4) {
#pragma unroll
                for (int jj = 0; jj < 4; ++jj)
                    atomicAdd(&sPool[lg * 64 + jq * 4 + jj], ps[jj]);
            } else {
#pragma unroll
                for (int jj = 0; jj < 4; ++jj)
                    atomicAdd(&xpz[(size_t)curg * 64 + jq * 4 + jj], ps[jj]);
            }
        }
    }
    __syncthreads();
    // flush LDS pool + BN partials
    {
        const int lg = tid >> 6, d = tid & 63;
        const float v = sPool[tid];
        if (v != 0.f) atomicAdd(&xpz[(size_t)(sGfirst + lg) * 64 + d], v);
    }
    if (tid < 64) {
        atomicAdd(&bnstats[tid], sSum[tid]);
        atomicAdd(&bnstats[64 + tid], sSq[tid]);
    }
}

// ============ finalize: xp[:, l*64+d] = sc*xpz + cnt*sh ; zero xpz ============
__global__ __launch_bounds__(256) void finalize_kernel(
    float* __restrict__ xp, const float* __restrict__ bnstats,
    const float* __restrict__ gamma, const float* __restrict__ beta,
    const int* __restrict__ cnt, float* __restrict__ xpz,
    int layer, int nG, float invN)
{
    const int i = blockIdx.x * 256 + threadIdx.x;
    if (i >= nG * 64) return;
    const int g = i >> 6, d = i & 63;
    const float mean = bnstats[d] * invN;
    const float var  = fmaxf(bnstats[64 + d] * invN - mean * mean, 0.f);
    const float sc = gamma[layer * 64 + d] * rsqrtf(var + BN_EPS);
    const float sh = beta[layer * 64 + d] - mean * sc;
    xp[(size_t)g * 192 + layer * 64 + d] = fmaf(sc, xpz[i], (float)cnt[g] * sh);
    xpz[i] = 0.f;
}

// ============ head ============
__global__ __launch_bounds__(256) void final_kernel(
    const float* __restrict__ xp, const float* __restrict__ lin_w,
    const float* __restrict__ lin_b, const float* __restrict__ fin_w,
    const float* __restrict__ fin_b, float* __restrict__ out, int nG)
{
    const int g = (blockIdx.x * 256 + threadIdx.x) >> 6;
    const int lane = threadIdx.x & 63;
    if (g >= nG) return;
    const float* xr = xp + (size_t)g * 192;
    float acc = lin_b[lane];
    for (int k = 0; k < 192; ++k) acc = fmaf(xr[k], lin_w[k * 64 + lane], acc);
    const float t = fmaxf(acc, 0.f);
    float o[10];
#pragma unroll
    for (int c = 0; c < 10; ++c) {
        float p = t * fin_w[lane * 10 + c];
#pragma unroll
        for (int off = 32; off > 0; off >>= 1) p += __shfl_xor(p, off);
        o[c] = p + fin_b[c];
    }
    float m = o[0];
#pragma unroll
    for (int c = 1; c < 10; ++c) m = fmaxf(m, o[c]);
    float Z = 0.f;
#pragma unroll
    for (int c = 0; c < 10; ++c) Z += expf(o[c] - m);
    const float lz = m + logf(Z);
#pragma unroll
    for (int c = 0; c < 10; ++c)
        if (lane == c) out[(size_t)g * 10 + c] = o[c] - lz;
}

extern "C" void kernel_launch(void* const* d_in, const int* in_sizes, int n_in,
                              void* d_out, int out_size, void* d_ws, size_t ws_size,
                              hipStream_t stream)
{
    const float* x     = (const float*)d_in[0];
    const int*   ei    = (const int*)d_in[1];
    const int*   batch = (const int*)d_in[2];
    const float* w1    = (const float*)d_in[3];
    const float* b1    = (const float*)d_in[4];
    const float* w2    = (const float*)d_in[5];
    const float* b2    = (const float*)d_in[6];
    const float* gamma = (const float*)d_in[7];
    const float* beta  = (const float*)d_in[8];
    const float* lin_w = (const float*)d_in[9];
    const float* lin_b = (const float*)d_in[10];
    const float* fin_w = (const float*)d_in[11];
    const float* fin_b = (const float*)d_in[12];
    float* out = (float*)d_out;

    const int N = in_sizes[0] / 64;
    const int E = in_sizes[1] / 2;
    const int L = in_sizes[3] / 4096;
    const int G = out_size / 10;
    const float invN = 1.0f / (float)N;

    char* ws = (char*)d_ws;
    size_t off = 0;
    auto alloc = [&](size_t bytes) -> void* {
        void* p = ws + off;
        off += (bytes + 255) & ~(size_t)255;
        return p;
    };
    unsigned short* z0 = (unsigned short*)alloc((size_t)N * 64 * 2);
    unsigned short* z1 = (unsigned short*)alloc((size_t)N * 64 * 2);
    float* xp      = (float*)alloc((size_t)G * 192 * 4);
    float* xpz     = (float*)alloc((size_t)G * 64 * 4);
    float* bnstats = (float*)alloc((size_t)L * 128 * 4);
    int*   cnt      = (int*)alloc((size_t)G * 4);
    int*   deg      = (int*)alloc((size_t)N * 4);
    int*   rowstart = (int*)alloc((size_t)N * 4);
    int*   cursor   = (int*)alloc((size_t)N * 4);
    int*   eidx     = (int*)alloc((size_t)E * 4);
    int*   blocksum = (int*)alloc(256 * 4);
    int*   blockoff = (int*)alloc(256 * 4);

    const int* srcIdx = ei;
    const int* dstIdx = ei + E;

    // ---- one-time setup (per call): CSR + graph-size histogram ----
    hipMemsetAsync(deg, 0, (size_t)N * 4, stream);
    hipMemsetAsync(bnstats, 0, (size_t)L * 128 * 4, stream);
    hipMemsetAsync(xpz, 0, (size_t)G * 64 * 4, stream);
    hipMemsetAsync(cnt, 0, (size_t)G * 4, stream);
    deg_kernel<<<(E + 255) / 256, 256, 0, stream>>>(dstIdx, deg, E);
    const int nblk = (N + SCAN_BS - 1) / SCAN_BS;
    scan_part_kernel<<<nblk, 256, 0, stream>>>(deg, rowstart, blocksum, N);
    scan_top_kernel<<<1, 64, 0, stream>>>(blocksum, blockoff, nblk);
    scan_add_kernel<<<(N + 255) / 256, 256, 0, stream>>>(rowstart, cursor, blockoff, N);
    fill_kernel<<<(E + 255) / 256, 256, 0, stream>>>(srcIdx, dstIdx, cursor, eidx, E);
    cnt_kernel<<<(N + 255) / 256, 256, 0, stream>>>(batch, cnt, N);

    const int nLayerBlk = (N + TN - 1) / TN;
    unsigned short* zprev = nullptr;
    unsigned short* zcur = z0;
    for (int l = 0; l < L; ++l) {
        gin_layer_kernel<<<nLayerBlk, 256, 0, stream>>>(
            (l == 0) ? x : nullptr,
            (l == 0) ? nullptr : zprev,
            (l == 0) ? nullptr : (bnstats + (size_t)(l - 1) * 128),
            gamma, beta, rowstart, deg, eidx, batch,
            w1, b1, w2, b2,
            zcur, bnstats + (size_t)l * 128, xpz, l, N, invN);
        finalize_kernel<<<(G * 64 + 255) / 256, 256, 0, stream>>>(
            xp, bnstats + (size_t)l * 128, gamma, beta, cnt, xpz, l, G, invN);
        zprev = zcur;
        zcur = (zcur == z0) ? z1 : z0;
    }
    final_kernel<<<(G * 64 + 255) / 256, 256, 0, stream>>>(xp, lin_w, lin_b,
                                                           fin_w, fin_b, out, G);
}

// Round 4
// 642.471 us; speedup vs baseline: 1.5356x; 1.5356x over previous
//
#include <hip/hip_runtime.h>

#define BN_EPS 1e-5f
#define TN 128       // nodes per MLP block
#define SCAN_BS 1024 // elements per scan block (256 thr x 4)

static __device__ __forceinline__ unsigned short f2bf(float f) {
    unsigned u = __float_as_uint(f);
    u += 0x7fff + ((u >> 16) & 1);   // round-to-nearest-even
    return (unsigned short)(u >> 16);
}
static __device__ __forceinline__ float bf2f(unsigned short s) {
    return __uint_as_float(((unsigned)s) << 16);
}

// ============ x -> bf16 ============
__global__ __launch_bounds__(256) void xbf_kernel(
    const float* __restrict__ x, unsigned short* __restrict__ xbf, int n4)
{
    const int i = blockIdx.x * 256 + threadIdx.x;
    if (i < n4) {
        const float4 v = reinterpret_cast<const float4*>(x)[i];
        ushort4 o;
        o.x = f2bf(v.x); o.y = f2bf(v.y); o.z = f2bf(v.z); o.w = f2bf(v.w);
        reinterpret_cast<ushort4*>(xbf)[i] = o;
    }
}

// ============ CSR build ============
__global__ __launch_bounds__(256) void deg_kernel(
    const int* __restrict__ dst, int* __restrict__ deg, int E)
{
    int e = blockIdx.x * 256 + threadIdx.x;
    if (e < E) atomicAdd(&deg[dst[e]], 1);
}

__global__ __launch_bounds__(256) void scan_part_kernel(
    const int* __restrict__ deg, int* __restrict__ rowstart,
    int* __restrict__ blocksum, int nN)
{
    __shared__ int lsum[256];
    const int t = threadIdx.x;
    const int base = blockIdx.x * SCAN_BS + t * 4;
    int v[4]; int s = 0;
#pragma unroll
    for (int k = 0; k < 4; ++k) {
        const int idx = base + k;
        v[k] = (idx < nN) ? deg[idx] : 0;
        s += v[k];
    }
    lsum[t] = s;
    __syncthreads();
    for (int off = 1; off < 256; off <<= 1) {
        const int x = lsum[t];
        const int y = (t >= off) ? lsum[t - off] : 0;
        __syncthreads();
        lsum[t] = x + y;
        __syncthreads();
    }
    int run = lsum[t] - s;
#pragma unroll
    for (int k = 0; k < 4; ++k) {
        const int idx = base + k;
        if (idx < nN) rowstart[idx] = run;
        run += v[k];
    }
    if (t == 255) blocksum[blockIdx.x] = lsum[255];
}

__global__ void scan_top_kernel(int* __restrict__ blocksum,
                                int* __restrict__ blockoff, int nblk)
{
    if (threadIdx.x == 0 && blockIdx.x == 0) {
        int run = 0;
        for (int i = 0; i < nblk; ++i) { blockoff[i] = run; run += blocksum[i]; }
    }
}

__global__ __launch_bounds__(256) void scan_add_kernel(
    int* __restrict__ rowstart, int* __restrict__ cursor,
    const int* __restrict__ blockoff, int nN)
{
    const int i = blockIdx.x * 256 + threadIdx.x;
    if (i < nN) {
        const int r = rowstart[i] + blockoff[i / SCAN_BS];
        rowstart[i] = r;
        cursor[i] = r;
    }
}

__global__ __launch_bounds__(256) void fill_kernel(
    const int* __restrict__ src, const int* __restrict__ dst,
    int* __restrict__ cursor, int* __restrict__ eidx, int E)
{
    const int e = blockIdx.x * 256 + threadIdx.x;
    if (e < E) {
        const int p = atomicAdd(&cursor[dst[e]], 1);
        eidx[p] = src[e];
    }
}

__global__ __launch_bounds__(256) void cnt_kernel(
    const int* __restrict__ batch, int* __restrict__ cnt, int nN)
{
    const int n = blockIdx.x * 256 + threadIdx.x;
    if (n < nN) atomicAdd(&cnt[batch[n]], 1);
}

// ============ aggregation: agg[n] = sc*(z[n] + sum_in z[s]) + (deg+1)*sh ============
// 1 node per wave; lanes 0-31 take even edges, 32-63 odd edges; ushort2 (2 feats)/lane.
__global__ __launch_bounds__(256) void agg_kernel(
    const unsigned short* __restrict__ z, const float* __restrict__ bnprev,
    const float* __restrict__ gamma, const float* __restrict__ beta,
    const int* __restrict__ rowstart, const int* __restrict__ deg,
    const int* __restrict__ eidx, float* __restrict__ agg,
    int layerPrev, int nN, float invN)
{
    const int node = blockIdx.x * 4 + (threadIdx.x >> 6);
    const int lane = threadIdx.x & 63;
    const int half = lane >> 5;
    const int fl = (lane & 31) * 2;      // feature pair base
    if (node >= nN) return;

    float ax = 0.f, ay = 0.f;
    const int rs = rowstart[node];
    const int d = deg[node];

    if (half == 0) {    // self term
        const ushort2 v = *reinterpret_cast<const ushort2*>(z + (size_t)node * 64 + fl);
        ax += bf2f(v.x); ay += bf2f(v.y);
    }

    int i = half;
    for (; i + 7 <= d; i += 8) {
        const int s0 = eidx[rs + i + 0];
        const int s1 = eidx[rs + i + 2];
        const int s2 = eidx[rs + i + 4];
        const int s3 = eidx[rs + i + 6];
        const ushort2 v0 = *reinterpret_cast<const ushort2*>(z + (size_t)s0 * 64 + fl);
        const ushort2 v1 = *reinterpret_cast<const ushort2*>(z + (size_t)s1 * 64 + fl);
        const ushort2 v2 = *reinterpret_cast<const ushort2*>(z + (size_t)s2 * 64 + fl);
        const ushort2 v3 = *reinterpret_cast<const ushort2*>(z + (size_t)s3 * 64 + fl);
        ax += (bf2f(v0.x) + bf2f(v1.x)) + (bf2f(v2.x) + bf2f(v3.x));
        ay += (bf2f(v0.y) + bf2f(v1.y)) + (bf2f(v2.y) + bf2f(v3.y));
    }
    for (; i < d; i += 2) {
        const int s = eidx[rs + i];
        const ushort2 v = *reinterpret_cast<const ushort2*>(z + (size_t)s * 64 + fl);
        ax += bf2f(v.x); ay += bf2f(v.y);
    }
    // fold odd-half into even-half
    ax += __shfl_xor(ax, 32);
    ay += __shfl_xor(ay, 32);

    if (half == 0) {
        float scx = 1.f, scy = 1.f, shx = 0.f, shy = 0.f;
        if (bnprev) {
            const float mx = bnprev[fl] * invN;
            const float my = bnprev[fl + 1] * invN;
            const float vx = fmaxf(bnprev[64 + fl] * invN - mx * mx, 0.f);
            const float vy = fmaxf(bnprev[64 + fl + 1] * invN - my * my, 0.f);
            const float gx = gamma[layerPrev * 64 + fl];
            const float gy = gamma[layerPrev * 64 + fl + 1];
            scx = gx * rsqrtf(vx + BN_EPS);
            scy = gy * rsqrtf(vy + BN_EPS);
            shx = beta[layerPrev * 64 + fl] - mx * scx;
            shy = beta[layerPrev * 64 + fl + 1] - my * scy;
        }
        const float c = (float)(d + 1);
        float2 o;
        o.x = fmaf(ax, scx, c * shx);
        o.y = fmaf(ay, scy, c * shy);
        *reinterpret_cast<float2*>(agg + (size_t)node * 64 + fl) = o;
    }
}

// ============ fused MLP: z = relu(relu(agg@W1+b1)@W2+b2) -> bf16, + BN stats + pool(z) ====
__global__ __launch_bounds__(256) void mlp_kernel(
    const float* __restrict__ agg, const int* __restrict__ batch,
    const float* __restrict__ w1, const float* __restrict__ b1,
    const float* __restrict__ w2, const float* __restrict__ b2,
    unsigned short* __restrict__ zout, float* __restrict__ bnstats,
    float* __restrict__ xpz, int layer, int nN)
{
    __shared__ float sA[64 * 132];     // A tile (feat-major, padded) / T tile
    __shared__ float sW[64 * 64];      // W1 then W2 (time-shared)
    __shared__ float sB1[64], sB2[64], sSum[64], sSq[64];
    __shared__ float sPool[4 * 64];
    __shared__ int sGfirst;
    const int tid = threadIdx.x;
    const int n0 = blockIdx.x * TN;

    const float4* w1v = reinterpret_cast<const float4*>(w1 + (size_t)layer * 4096);
    float4* sWv = reinterpret_cast<float4*>(sW);
    for (int i = tid; i < 1024; i += 256) sWv[i] = w1v[i];
    if (tid < 64) {
        sB1[tid] = b1[layer * 64 + tid];
        sB2[tid] = b2[layer * 64 + tid];
        sSum[tid] = 0.f; sSq[tid] = 0.f;
    }
    sPool[tid] = 0.f;
    if (tid == 0) sGfirst = batch[n0];

    // stage A transposed: sA[k*132 + n]
    for (int i = tid; i < TN * 16; i += 256) {
        const int n = i >> 4;
        const int k4 = i & 15;
        const int node = n0 + n;
        float4 v = make_float4(0.f, 0.f, 0.f, 0.f);
        if (node < nN)
            v = *reinterpret_cast<const float4*>(agg + (size_t)node * 64 + k4 * 4);
        const int k = k4 * 4;
        sA[(k + 0) * 132 + n] = v.x;
        sA[(k + 1) * 132 + n] = v.y;
        sA[(k + 2) * 132 + n] = v.z;
        sA[(k + 3) * 132 + n] = v.w;
    }
    __syncthreads();

    const int jq = tid & 15;
    const int no = tid >> 4;
    float acc[8][4];

    // ---- mm1: T = relu(A @ W1 + b1) ----
#pragma unroll
    for (int nn = 0; nn < 8; ++nn)
#pragma unroll
        for (int jj = 0; jj < 4; ++jj) acc[nn][jj] = sB1[jq * 4 + jj];
#pragma unroll 4
    for (int k = 0; k < 64; ++k) {
        const float4 a0 = *reinterpret_cast<const float4*>(&sA[k * 132 + no * 8]);
        const float4 a1 = *reinterpret_cast<const float4*>(&sA[k * 132 + no * 8 + 4]);
        const float4 wv4 = *reinterpret_cast<const float4*>(&sW[k * 64 + jq * 4]);
        const float av[8] = {a0.x, a0.y, a0.z, a0.w, a1.x, a1.y, a1.z, a1.w};
        const float wj[4] = {wv4.x, wv4.y, wv4.z, wv4.w};
#pragma unroll
        for (int nn = 0; nn < 8; ++nn)
#pragma unroll
            for (int jj = 0; jj < 4; ++jj) acc[nn][jj] = fmaf(av[nn], wj[jj], acc[nn][jj]);
    }
    __syncthreads();

    // write T (relu) into sA; load W2
#pragma unroll
    for (int nn = 0; nn < 8; ++nn)
#pragma unroll
        for (int jj = 0; jj < 4; ++jj)
            sA[(jq * 4 + jj) * 132 + no * 8 + nn] = fmaxf(acc[nn][jj], 0.f);
    const float4* w2v = reinterpret_cast<const float4*>(w2 + (size_t)layer * 4096);
    for (int i = tid; i < 1024; i += 256) sWv[i] = w2v[i];
    __syncthreads();

    // ---- mm2: Z = relu(T @ W2 + b2) ----
#pragma unroll
    for (int nn = 0; nn < 8; ++nn)
#pragma unroll
        for (int jj = 0; jj < 4; ++jj) acc[nn][jj] = sB2[jq * 4 + jj];
#pragma unroll 4
    for (int k = 0; k < 64; ++k) {
        const float4 a0 = *reinterpret_cast<const float4*>(&sA[k * 132 + no * 8]);
        const float4 a1 = *reinterpret_cast<const float4*>(&sA[k * 132 + no * 8 + 4]);
        const float4 wv4 = *reinterpret_cast<const float4*>(&sW[k * 64 + jq * 4]);
        const float av[8] = {a0.x, a0.y, a0.z, a0.w, a1.x, a1.y, a1.z, a1.w};
        const float wj[4] = {wv4.x, wv4.y, wv4.z, wv4.w};
#pragma unroll
        for (int nn = 0; nn < 8; ++nn)
#pragma unroll
            for (int jj = 0; jj < 4; ++jj) acc[nn][jj] = fmaf(av[nn], wj[jj], acc[nn][jj]);
    }

    // ---- epilogue: relu, z store (bf16), BN partials, run-length pool ----
#pragma unroll
    for (int nn = 0; nn < 8; ++nn) {
        const int node = n0 + no * 8 + nn;
#pragma unroll
        for (int jj = 0; jj < 4; ++jj) acc[nn][jj] = fmaxf(acc[nn][jj], 0.f);
        if (node < nN) {
            ushort4 o;
            o.x = f2bf(acc[nn][0]); o.y = f2bf(acc[nn][1]);
            o.z = f2bf(acc[nn][2]); o.w = f2bf(acc[nn][3]);
            *reinterpret_cast<ushort4*>(zout + (size_t)node * 64 + jq * 4) = o;
        }
    }
#pragma unroll
    for (int jj = 0; jj < 4; ++jj) {
        float s = 0.f, q = 0.f;
#pragma unroll
        for (int nn = 0; nn < 8; ++nn) {
            const int node = n0 + no * 8 + nn;
            if (node < nN) { const float v = acc[nn][jj]; s += v; q += v * v; }
        }
        atomicAdd(&sSum[jq * 4 + jj], s);
        atomicAdd(&sSq[jq * 4 + jj], q);
    }
    {
        int curg = -1;
        float ps[4] = {0.f, 0.f, 0.f, 0.f};
        const int gfirst = sGfirst;
#pragma unroll
        for (int nn = 0; nn < 8; ++nn) {
            const int node = n0 + no * 8 + nn;
            if (node < nN) {
                const int g = batch[node];
                if (g != curg) {
                    if (curg >= 0) {
                        const int lg = curg - gfirst;
                        if (lg < 4) {
#pragma unroll
                            for (int jj = 0; jj < 4; ++jj)
                                atomicAdd(&sPool[lg * 64 + jq * 4 + jj], ps[jj]);
                        } else {
#pragma unroll
                            for (int jj = 0; jj < 4; ++jj)
                                atomicAdd(&xpz[(size_t)curg * 64 + jq * 4 + jj], ps[jj]);
                        }
                    }
                    curg = g;
                    ps[0] = ps[1] = ps[2] = ps[3] = 0.f;
                }
#pragma unroll
                for (int jj = 0; jj < 4; ++jj) ps[jj] += acc[nn][jj];
            }
        }
        if (curg >= 0) {
            const int lg = curg - gfirst;
            if (lg < 4) {
#pragma unroll
                for (int jj = 0; jj < 4; ++jj)
                    atomicAdd(&sPool[lg * 64 + jq * 4 + jj], ps[jj]);
            } else {
#pragma unroll
                for (int jj = 0; jj < 4; ++jj)
                    atomicAdd(&xpz[(size_t)curg * 64 + jq * 4 + jj], ps[jj]);
            }
        }
    }
    __syncthreads();
    {
        const int lg = tid >> 6, d = tid & 63;
        const float v = sPool[tid];
        if (v != 0.f) atomicAdd(&xpz[(size_t)(sGfirst + lg) * 64 + d], v);
    }
    if (tid < 64) {
        atomicAdd(&bnstats[tid], sSum[tid]);
        atomicAdd(&bnstats[64 + tid], sSq[tid]);
    }
}

// ============ finalize: xp[:, l*64+d] = sc*xpz + cnt*sh ; zero xpz ============
__global__ __launch_bounds__(256) void finalize_kernel(
    float* __restrict__ xp, const float* __restrict__ bnstats,
    const float* __restrict__ gamma, const float* __restrict__ beta,
    const int* __restrict__ cnt, float* __restrict__ xpz,
    int layer, int nG, float invN)
{
    const int i = blockIdx.x * 256 + threadIdx.x;
    if (i >= nG * 64) return;
    const int g = i >> 6, d = i & 63;
    const float mean = bnstats[d] * invN;
    const float var  = fmaxf(bnstats[64 + d] * invN - mean * mean, 0.f);
    const float sc = gamma[layer * 64 + d] * rsqrtf(var + BN_EPS);
    const float sh = beta[layer * 64 + d] - mean * sc;
    xp[(size_t)g * 192 + layer * 64 + d] = fmaf(sc, xpz[i], (float)cnt[g] * sh);
    xpz[i] = 0.f;
}

// ============ head ============
__global__ __launch_bounds__(256) void final_kernel(
    const float* __restrict__ xp, const float* __restrict__ lin_w,
    const float* __restrict__ lin_b, const float* __restrict__ fin_w,
    const float* __restrict__ fin_b, float* __restrict__ out, int nG)
{
    const int g = (blockIdx.x * 256 + threadIdx.x) >> 6;
    const int lane = threadIdx.x & 63;
    if (g >= nG) return;
    const float* xr = xp + (size_t)g * 192;
    float acc = lin_b[lane];
    for (int k = 0; k < 192; ++k) acc = fmaf(xr[k], lin_w[k * 64 + lane], acc);
    const float t = fmaxf(acc, 0.f);
    float o[10];
#pragma unroll
    for (int c = 0; c < 10; ++c) {
        float p = t * fin_w[lane * 10 + c];
#pragma unroll
        for (int off = 32; off > 0; off >>= 1) p += __shfl_xor(p, off);
        o[c] = p + fin_b[c];
    }
    float m = o[0];
#pragma unroll
    for (int c = 1; c < 10; ++c) m = fmaxf(m, o[c]);
    float Z = 0.f;
#pragma unroll
    for (int c = 0; c < 10; ++c) Z += expf(o[c] - m);
    const float lz = m + logf(Z);
#pragma unroll
    for (int c = 0; c < 10; ++c)
        if (lane == c) out[(size_t)g * 10 + c] = o[c] - lz;
}

extern "C" void kernel_launch(void* const* d_in, const int* in_sizes, int n_in,
                              void* d_out, int out_size, void* d_ws, size_t ws_size,
                              hipStream_t stream)
{
    const float* x     = (const float*)d_in[0];
    const int*   ei    = (const int*)d_in[1];
    const int*   batch = (const int*)d_in[2];
    const float* w1    = (const float*)d_in[3];
    const float* b1    = (const float*)d_in[4];
    const float* w2    = (const float*)d_in[5];
    const float* b2    = (const float*)d_in[6];
    const float* gamma = (const float*)d_in[7];
    const float* beta  = (const float*)d_in[8];
    const float* lin_w = (const float*)d_in[9];
    const float* lin_b = (const float*)d_in[10];
    const float* fin_w = (const float*)d_in[11];
    const float* fin_b = (const float*)d_in[12];
    float* out = (float*)d_out;

    const int N = in_sizes[0] / 64;
    const int E = in_sizes[1] / 2;
    const int L = in_sizes[3] / 4096;
    const int G = out_size / 10;
    const float invN = 1.0f / (float)N;

    char* ws = (char*)d_ws;
    size_t off = 0;
    auto alloc = [&](size_t bytes) -> void* {
        void* p = ws + off;
        off += (bytes + 255) & ~(size_t)255;
        return p;
    };
    unsigned short* xbf = (unsigned short*)alloc((size_t)N * 64 * 2);
    unsigned short* z0  = (unsigned short*)alloc((size_t)N * 64 * 2);
    unsigned short* z1  = (unsigned short*)alloc((size_t)N * 64 * 2);
    float* aggbuf  = (float*)alloc((size_t)N * 64 * 4);
    float* xp      = (float*)alloc((size_t)G * 192 * 4);
    float* xpz     = (float*)alloc((size_t)G * 64 * 4);
    float* bnstats = (float*)alloc((size_t)L * 128 * 4);
    int*   cnt      = (int*)alloc((size_t)G * 4);
    int*   deg      = (int*)alloc((size_t)N * 4);
    int*   rowstart = (int*)alloc((size_t)N * 4);
    int*   cursor   = (int*)alloc((size_t)N * 4);
    int*   eidx     = (int*)alloc((size_t)E * 4);
    int*   blocksum = (int*)alloc(256 * 4);
    int*   blockoff = (int*)alloc(256 * 4);

    const int* srcIdx = ei;
    const int* dstIdx = ei + E;

    // ---- setup: CSR + counts + x->bf16 ----
    hipMemsetAsync(deg, 0, (size_t)N * 4, stream);
    hipMemsetAsync(bnstats, 0, (size_t)L * 128 * 4, stream);
    hipMemsetAsync(xpz, 0, (size_t)G * 64 * 4, stream);
    hipMemsetAsync(cnt, 0, (size_t)G * 4, stream);
    deg_kernel<<<(E + 255) / 256, 256, 0, stream>>>(dstIdx, deg, E);
    const int nblk = (N + SCAN_BS - 1) / SCAN_BS;
    scan_part_kernel<<<nblk, 256, 0, stream>>>(deg, rowstart, blocksum, N);
    scan_top_kernel<<<1, 64, 0, stream>>>(blocksum, blockoff, nblk);
    scan_add_kernel<<<(N + 255) / 256, 256, 0, stream>>>(rowstart, cursor, blockoff, N);
    fill_kernel<<<(E + 255) / 256, 256, 0, stream>>>(srcIdx, dstIdx, cursor, eidx, E);
    cnt_kernel<<<(N + 255) / 256, 256, 0, stream>>>(batch, cnt, N);
    xbf_kernel<<<(N * 16 + 255) / 256, 256, 0, stream>>>(x, xbf, N * 16);

    const int nAggBlk = (N + 3) / 4;
    const int nMlpBlk = (N + TN - 1) / TN;
    unsigned short* zprev = xbf;
    unsigned short* zcur = z0;
    for (int l = 0; l < L; ++l) {
        agg_kernel<<<nAggBlk, 256, 0, stream>>>(
            zprev,
            (l == 0) ? nullptr : (bnstats + (size_t)(l - 1) * 128),
            gamma, beta, rowstart, deg, eidx, aggbuf, l - 1, N, invN);
        mlp_kernel<<<nMlpBlk, 256, 0, stream>>>(
            aggbuf, batch, w1, b1, w2, b2,
            zcur, bnstats + (size_t)l * 128, xpz, l, N);
        finalize_kernel<<<(G * 64 + 255) / 256, 256, 0, stream>>>(
            xp, bnstats + (size_t)l * 128, gamma, beta, cnt, xpz, l, G, invN);
        zprev = zcur;
        zcur = (zcur == z0) ? z1 : z0;
    }
    final_kernel<<<(G * 64 + 255) / 256, 256, 0, stream>>>(xp, lin_w, lin_b,
                                                           fin_w, fin_b, out, G);
}

// Round 5
// 453.802 us; speedup vs baseline: 2.1740x; 1.4158x over previous
//
#include <hip/hip_runtime.h>

#define BN_EPS 1e-5f
#define TN 128        // nodes per MLP block
#define NPB 256       // nodes per bucket
#define BCAP 8192     // LDS edge cap per bucket (avg 4096)
#define BH_EPB 8192   // edges per block, histogram
#define PT_EPB 4096   // edges per block, partition

static __device__ __forceinline__ unsigned short f2bf(float f) {
    unsigned u = __float_as_uint(f);
    u += 0x7fff + ((u >> 16) & 1);
    return (unsigned short)(u >> 16);
}
static __device__ __forceinline__ float bf2f(unsigned short s) {
    return __uint_as_float(((unsigned)s) << 16);
}

// ============ x -> bf16 ============
__global__ __launch_bounds__(256) void xbf_kernel(
    const float* __restrict__ x, unsigned short* __restrict__ xbf, int n4)
{
    const int i = blockIdx.x * 256 + threadIdx.x;
    if (i < n4) {
        const float4 v = reinterpret_cast<const float4*>(x)[i];
        ushort4 o;
        o.x = f2bf(v.x); o.y = f2bf(v.y); o.z = f2bf(v.z); o.w = f2bf(v.w);
        reinterpret_cast<ushort4*>(xbf)[i] = o;
    }
}

// ============ bucket histogram: bucketCnt[dst>>8]++ ============
__global__ __launch_bounds__(256) void bh_kernel(
    const int* __restrict__ dst, int* __restrict__ bucketCnt, int E, int NB)
{
    __shared__ int lh[512];
    const int tid = threadIdx.x;
    for (int i = tid; i < NB; i += 256) lh[i] = 0;
    __syncthreads();
    const int base = blockIdx.x * BH_EPB;
#pragma unroll
    for (int k = 0; k < BH_EPB / 256; ++k) {
        const int e = base + k * 256 + tid;
        if (e < E) atomicAdd(&lh[dst[e] >> 8], 1);
    }
    __syncthreads();
    for (int i = tid; i < NB; i += 256) {
        const int c = lh[i];
        if (c > 0) atomicAdd(&bucketCnt[i], c);
    }
}

// ============ bucket scan (1 block, 512 thr; NB <= 512) ============
__global__ __launch_bounds__(512) void bscan_kernel(
    const int* __restrict__ bucketCnt, int* __restrict__ bucketStart,
    int* __restrict__ bucketCursor, int NB)
{
    __shared__ int ls[512];
    const int t = threadIdx.x;
    const int v = (t < NB) ? bucketCnt[t] : 0;
    ls[t] = v;
    __syncthreads();
    for (int off = 1; off < 512; off <<= 1) {
        const int a = ls[t];
        const int b = (t >= off) ? ls[t - off] : 0;
        __syncthreads();
        ls[t] = a + b;
        __syncthreads();
    }
    const int excl = ls[t] - v;
    if (t < NB) { bucketStart[t] = excl; bucketCursor[t] = excl; }
    if (t == 511) bucketStart[NB] = ls[511];
}

// ============ partition: part[] = (src<<8)|dstloc, bucket-contiguous ============
__global__ __launch_bounds__(256) void part_kernel(
    const int* __restrict__ src, const int* __restrict__ dst,
    int* __restrict__ bucketCursor, unsigned* __restrict__ part, int E, int NB)
{
    __shared__ int lh[512];
    __shared__ int lbase[512];
    const int tid = threadIdx.x;
    const int base = blockIdx.x * PT_EPB;
    for (int i = tid; i < NB; i += 256) lh[i] = 0;
    __syncthreads();
#pragma unroll
    for (int k = 0; k < PT_EPB / 256; ++k) {
        const int e = base + k * 256 + tid;
        if (e < E) atomicAdd(&lh[dst[e] >> 8], 1);
    }
    __syncthreads();
    for (int i = tid; i < NB; i += 256) {
        const int c = lh[i];
        lbase[i] = (c > 0) ? atomicAdd(&bucketCursor[i], c) : 0;
        lh[i] = 0;  // reuse as local cursor
    }
    __syncthreads();
#pragma unroll
    for (int k = 0; k < PT_EPB / 256; ++k) {
        const int e = base + k * 256 + tid;
        if (e < E) {
            const int d = dst[e];
            const int b = d >> 8;
            const int off = atomicAdd(&lh[b], 1);
            part[lbase[b] + off] = ((unsigned)src[e] << 8) | (unsigned)(d & 255);
        }
    }
}

// ============ per-bucket CSR build: deg/rowstart/eidx ============
__global__ __launch_bounds__(256) void bcsr_kernel(
    const unsigned* __restrict__ part, const int* __restrict__ bucketStart,
    int* __restrict__ deg, int* __restrict__ rowstart,
    int* __restrict__ eidx, int nN)
{
    __shared__ unsigned sSrc[BCAP];
    __shared__ int ldeg[256], ls[256], lcur[256];
    const int b = blockIdx.x;
    const int tid = threadIdx.x;
    const int sStart = bucketStart[b];
    const int cnt = bucketStart[b + 1] - sStart;
    const bool ldsok = (cnt <= BCAP);

    ldeg[tid] = 0;
    __syncthreads();
    for (int i = tid; i < cnt; i += 256) {
        const unsigned v = part[sStart + i];
        if (ldsok) sSrc[i] = v;
        atomicAdd(&ldeg[v & 255u], 1);
    }
    __syncthreads();
    // exclusive scan of ldeg
    const int dv = ldeg[tid];
    ls[tid] = dv;
    __syncthreads();
    for (int off = 1; off < 256; off <<= 1) {
        const int a = ls[tid];
        const int c = (tid >= off) ? ls[tid - off] : 0;
        __syncthreads();
        ls[tid] = a + c;
        __syncthreads();
    }
    const int excl = ls[tid] - dv;
    lcur[tid] = excl;
    const int node = b * NPB + tid;
    if (node < nN) {
        deg[node] = dv;
        rowstart[node] = sStart + excl;
    }
    __syncthreads();
    for (int i = tid; i < cnt; i += 256) {
        const unsigned v = ldsok ? sSrc[i] : part[sStart + i];
        const int dloc = (int)(v & 255u);
        const int p = atomicAdd(&lcur[dloc], 1);
        eidx[sStart + p] = (int)(v >> 8);
    }
}

__global__ __launch_bounds__(256) void cnt_kernel(
    const int* __restrict__ batch, int* __restrict__ cnt, int nN)
{
    const int n = blockIdx.x * 256 + threadIdx.x;
    if (n < nN) atomicAdd(&cnt[batch[n]], 1);
}

// ============ aggregation: agg[n] = sc*(z[n] + sum_in z[s]) + (deg+1)*sh ============
// 1 node/wave; quarter-wave (16 lanes x ushort4 = 128B) per edge; 4 edges in flight.
__global__ __launch_bounds__(256) void agg_kernel(
    const unsigned short* __restrict__ z, const float* __restrict__ scsh,
    const int* __restrict__ rowstart, const int* __restrict__ deg,
    const int* __restrict__ eidx, float* __restrict__ agg, int nN)
{
    const int node = blockIdx.x * 4 + (threadIdx.x >> 6);
    if (node >= nN) return;
    const int lane = threadIdx.x & 63;
    const int q = lane >> 4;          // edge slot within group of 4
    const int fr = (lane & 15) * 4;   // feature quad
    const int rs = rowstart[node];
    const int d = deg[node];

    float a0 = 0.f, a1 = 0.f, a2 = 0.f, a3 = 0.f;
    if (q == 0) {
        const ushort4 v = *reinterpret_cast<const ushort4*>(z + (size_t)node * 64 + fr);
        a0 = bf2f(v.x); a1 = bf2f(v.y); a2 = bf2f(v.z); a3 = bf2f(v.w);
    }
    for (int i = 0; i < d; i += 16) {
        const int j0 = i + q, j1 = j0 + 4, j2 = j0 + 8, j3 = j0 + 12;
        const int c0 = min(j0, d - 1), c1 = min(j1, d - 1);
        const int c2 = min(j2, d - 1), c3 = min(j3, d - 1);
        const int s0 = eidx[rs + c0], s1 = eidx[rs + c1];
        const int s2 = eidx[rs + c2], s3 = eidx[rs + c3];
        const ushort4 v0 = *reinterpret_cast<const ushort4*>(z + (size_t)s0 * 64 + fr);
        const ushort4 v1 = *reinterpret_cast<const ushort4*>(z + (size_t)s1 * 64 + fr);
        const ushort4 v2 = *reinterpret_cast<const ushort4*>(z + (size_t)s2 * 64 + fr);
        const ushort4 v3 = *reinterpret_cast<const ushort4*>(z + (size_t)s3 * 64 + fr);
        const float w0 = (j0 < d) ? 1.f : 0.f;
        const float w1 = (j1 < d) ? 1.f : 0.f;
        const float w2 = (j2 < d) ? 1.f : 0.f;
        const float w3 = (j3 < d) ? 1.f : 0.f;
        a0 = fmaf(w0, bf2f(v0.x), a0); a1 = fmaf(w0, bf2f(v0.y), a1);
        a2 = fmaf(w0, bf2f(v0.z), a2); a3 = fmaf(w0, bf2f(v0.w), a3);
        a0 = fmaf(w1, bf2f(v1.x), a0); a1 = fmaf(w1, bf2f(v1.y), a1);
        a2 = fmaf(w1, bf2f(v1.z), a2); a3 = fmaf(w1, bf2f(v1.w), a3);
        a0 = fmaf(w2, bf2f(v2.x), a0); a1 = fmaf(w2, bf2f(v2.y), a1);
        a2 = fmaf(w2, bf2f(v2.z), a2); a3 = fmaf(w2, bf2f(v2.w), a3);
        a0 = fmaf(w3, bf2f(v3.x), a0); a1 = fmaf(w3, bf2f(v3.y), a1);
        a2 = fmaf(w3, bf2f(v3.z), a2); a3 = fmaf(w3, bf2f(v3.w), a3);
    }
    a0 += __shfl_xor(a0, 16); a0 += __shfl_xor(a0, 32);
    a1 += __shfl_xor(a1, 16); a1 += __shfl_xor(a1, 32);
    a2 += __shfl_xor(a2, 16); a2 += __shfl_xor(a2, 32);
    a3 += __shfl_xor(a3, 16); a3 += __shfl_xor(a3, 32);
    if (lane < 16) {
        float4 sc = make_float4(1.f, 1.f, 1.f, 1.f);
        float4 sh = make_float4(0.f, 0.f, 0.f, 0.f);
        if (scsh) {
            sc = *reinterpret_cast<const float4*>(scsh + fr);
            sh = *reinterpret_cast<const float4*>(scsh + 64 + fr);
        }
        const float c = (float)(d + 1);
        float4 o;
        o.x = fmaf(a0, sc.x, c * sh.x);
        o.y = fmaf(a1, sc.y, c * sh.y);
        o.z = fmaf(a2, sc.z, c * sh.z);
        o.w = fmaf(a3, sc.w, c * sh.w);
        *reinterpret_cast<float4*>(agg + (size_t)node * 64 + fr) = o;
    }
}

// ============ fused MLP: z = relu(relu(agg@W1+b1)@W2+b2) -> bf16, + BN stats + pool(z) ====
__global__ __launch_bounds__(256) void mlp_kernel(
    const float* __restrict__ agg, const int* __restrict__ batch,
    const float* __restrict__ w1, const float* __restrict__ b1,
    const float* __restrict__ w2, const float* __restrict__ b2,
    unsigned short* __restrict__ zout, float* __restrict__ bnstats,
    float* __restrict__ xpz, int layer, int nN)
{
    __shared__ float sA[64 * 132];
    __shared__ float sW[64 * 64];
    __shared__ float sB1[64], sB2[64], sSum[64], sSq[64];
    __shared__ float sPool[4 * 64];
    __shared__ int sGfirst;
    const int tid = threadIdx.x;
    const int n0 = blockIdx.x * TN;

    const float4* w1v = reinterpret_cast<const float4*>(w1 + (size_t)layer * 4096);
    float4* sWv = reinterpret_cast<float4*>(sW);
    for (int i = tid; i < 1024; i += 256) sWv[i] = w1v[i];
    if (tid < 64) {
        sB1[tid] = b1[layer * 64 + tid];
        sB2[tid] = b2[layer * 64 + tid];
        sSum[tid] = 0.f; sSq[tid] = 0.f;
    }
    sPool[tid] = 0.f;
    if (tid == 0) sGfirst = batch[n0];

    for (int i = tid; i < TN * 16; i += 256) {
        const int n = i >> 4;
        const int k4 = i & 15;
        const int node = n0 + n;
        float4 v = make_float4(0.f, 0.f, 0.f, 0.f);
        if (node < nN)
            v = *reinterpret_cast<const float4*>(agg + (size_t)node * 64 + k4 * 4);
        const int k = k4 * 4;
        sA[(k + 0) * 132 + n] = v.x;
        sA[(k + 1) * 132 + n] = v.y;
        sA[(k + 2) * 132 + n] = v.z;
        sA[(k + 3) * 132 + n] = v.w;
    }
    __syncthreads();

    const int jq = tid & 15;
    const int no = tid >> 4;
    float acc[8][4];

#pragma unroll
    for (int nn = 0; nn < 8; ++nn)
#pragma unroll
        for (int jj = 0; jj < 4; ++jj) acc[nn][jj] = sB1[jq * 4 + jj];
#pragma unroll 4
    for (int k = 0; k < 64; ++k) {
        const float4 a0 = *reinterpret_cast<const float4*>(&sA[k * 132 + no * 8]);
        const float4 a1 = *reinterpret_cast<const float4*>(&sA[k * 132 + no * 8 + 4]);
        const float4 wv4 = *reinterpret_cast<const float4*>(&sW[k * 64 + jq * 4]);
        const float av[8] = {a0.x, a0.y, a0.z, a0.w, a1.x, a1.y, a1.z, a1.w};
        const float wj[4] = {wv4.x, wv4.y, wv4.z, wv4.w};
#pragma unroll
        for (int nn = 0; nn < 8; ++nn)
#pragma unroll
            for (int jj = 0; jj < 4; ++jj) acc[nn][jj] = fmaf(av[nn], wj[jj], acc[nn][jj]);
    }
    __syncthreads();

#pragma unroll
    for (int nn = 0; nn < 8; ++nn)
#pragma unroll
        for (int jj = 0; jj < 4; ++jj)
            sA[(jq * 4 + jj) * 132 + no * 8 + nn] = fmaxf(acc[nn][jj], 0.f);
    const float4* w2v = reinterpret_cast<const float4*>(w2 + (size_t)layer * 4096);
    for (int i = tid; i < 1024; i += 256) sWv[i] = w2v[i];
    __syncthreads();

#pragma unroll
    for (int nn = 0; nn < 8; ++nn)
#pragma unroll
        for (int jj = 0; jj < 4; ++jj) acc[nn][jj] = sB2[jq * 4 + jj];
#pragma unroll 4
    for (int k = 0; k < 64; ++k) {
        const float4 a0 = *reinterpret_cast<const float4*>(&sA[k * 132 + no * 8]);
        const float4 a1 = *reinterpret_cast<const float4*>(&sA[k * 132 + no * 8 + 4]);
        const float4 wv4 = *reinterpret_cast<const float4*>(&sW[k * 64 + jq * 4]);
        const float av[8] = {a0.x, a0.y, a0.z, a0.w, a1.x, a1.y, a1.z, a1.w};
        const float wj[4] = {wv4.x, wv4.y, wv4.z, wv4.w};
#pragma unroll
        for (int nn = 0; nn < 8; ++nn)
#pragma unroll
            for (int jj = 0; jj < 4; ++jj) acc[nn][jj] = fmaf(av[nn], wj[jj], acc[nn][jj]);
    }

#pragma unroll
    for (int nn = 0; nn < 8; ++nn) {
        const int node = n0 + no * 8 + nn;
#pragma unroll
        for (int jj = 0; jj < 4; ++jj) acc[nn][jj] = fmaxf(acc[nn][jj], 0.f);
        if (node < nN) {
            ushort4 o;
            o.x = f2bf(acc[nn][0]); o.y = f2bf(acc[nn][1]);
            o.z = f2bf(acc[nn][2]); o.w = f2bf(acc[nn][3]);
            *reinterpret_cast<ushort4*>(zout + (size_t)node * 64 + jq * 4) = o;
        }
    }
#pragma unroll
    for (int jj = 0; jj < 4; ++jj) {
        float s = 0.f, qq = 0.f;
#pragma unroll
        for (int nn = 0; nn < 8; ++nn) {
            const int node = n0 + no * 8 + nn;
            if (node < nN) { const float v = acc[nn][jj]; s += v; qq += v * v; }
        }
        atomicAdd(&sSum[jq * 4 + jj], s);
        atomicAdd(&sSq[jq * 4 + jj], qq);
    }
    {
        int curg = -1;
        float ps[4] = {0.f, 0.f, 0.f, 0.f};
        const int gfirst = sGfirst;
#pragma unroll
        for (int nn = 0; nn < 8; ++nn) {
            const int node = n0 + no * 8 + nn;
            if (node < nN) {
                const int g = batch[node];
                if (g != curg) {
                    if (curg >= 0) {
                        const int lg = curg - gfirst;
                        if (lg < 4) {
#pragma unroll
                            for (int jj = 0; jj < 4; ++jj)
                                atomicAdd(&sPool[lg * 64 + jq * 4 + jj], ps[jj]);
                        } else {
#pragma unroll
                            for (int jj = 0; jj < 4; ++jj)
                                atomicAdd(&xpz[(size_t)curg * 64 + jq * 4 + jj], ps[jj]);
                        }
                    }
                    curg = g;
                    ps[0] = ps[1] = ps[2] = ps[3] = 0.f;
                }
#pragma unroll
                for (int jj = 0; jj < 4; ++jj) ps[jj] += acc[nn][jj];
            }
        }
        if (curg >= 0) {
            const int lg = curg - gfirst;
            if (lg < 4) {
#pragma unroll
                for (int jj = 0; jj < 4; ++jj)
                    atomicAdd(&sPool[lg * 64 + jq * 4 + jj], ps[jj]);
            } else {
#pragma unroll
                for (int jj = 0; jj < 4; ++jj)
                    atomicAdd(&xpz[(size_t)curg * 64 + jq * 4 + jj], ps[jj]);
            }
        }
    }
    __syncthreads();
    {
        const int lg = tid >> 6, d = tid & 63;
        const float v = sPool[tid];
        if (v != 0.f) atomicAdd(&xpz[(size_t)(sGfirst + lg) * 64 + d], v);
    }
    if (tid < 64) {
        atomicAdd(&bnstats[tid], sSum[tid]);
        atomicAdd(&bnstats[64 + tid], sSq[tid]);
    }
}

// ============ finalize: xp = sc*xpz + cnt*sh ; emit scsh for next layer; zero xpz ====
__global__ __launch_bounds__(256) void finalize_kernel(
    float* __restrict__ xp, const float* __restrict__ bnstats,
    const float* __restrict__ gamma, const float* __restrict__ beta,
    const int* __restrict__ cnt, float* __restrict__ xpz,
    float* __restrict__ scsh, int layer, int nG, float invN)
{
    const int i = blockIdx.x * 256 + threadIdx.x;
    if (i >= nG * 64) return;
    const int g = i >> 6, d = i & 63;
    const float mean = bnstats[d] * invN;
    const float var  = fmaxf(bnstats[64 + d] * invN - mean * mean, 0.f);
    const float sc = gamma[layer * 64 + d] * rsqrtf(var + BN_EPS);
    const float sh = beta[layer * 64 + d] - mean * sc;
    if (g == 0) { scsh[d] = sc; scsh[64 + d] = sh; }
    xp[(size_t)g * 192 + layer * 64 + d] = fmaf(sc, xpz[i], (float)cnt[g] * sh);
    xpz[i] = 0.f;
}

// ============ head ============
__global__ __launch_bounds__(256) void final_kernel(
    const float* __restrict__ xp, const float* __restrict__ lin_w,
    const float* __restrict__ lin_b, const float* __restrict__ fin_w,
    const float* __restrict__ fin_b, float* __restrict__ out, int nG)
{
    const int g = (blockIdx.x * 256 + threadIdx.x) >> 6;
    const int lane = threadIdx.x & 63;
    if (g >= nG) return;
    const float* xr = xp + (size_t)g * 192;
    float acc = lin_b[lane];
    for (int k = 0; k < 192; ++k) acc = fmaf(xr[k], lin_w[k * 64 + lane], acc);
    const float t = fmaxf(acc, 0.f);
    float o[10];
#pragma unroll
    for (int c = 0; c < 10; ++c) {
        float p = t * fin_w[lane * 10 + c];
#pragma unroll
        for (int off = 32; off > 0; off >>= 1) p += __shfl_xor(p, off);
        o[c] = p + fin_b[c];
    }
    float m = o[0];
#pragma unroll
    for (int c = 1; c < 10; ++c) m = fmaxf(m, o[c]);
    float Z = 0.f;
#pragma unroll
    for (int c = 0; c < 10; ++c) Z += expf(o[c] - m);
    const float lz = m + logf(Z);
#pragma unroll
    for (int c = 0; c < 10; ++c)
        if (lane == c) out[(size_t)g * 10 + c] = o[c] - lz;
}

extern "C" void kernel_launch(void* const* d_in, const int* in_sizes, int n_in,
                              void* d_out, int out_size, void* d_ws, size_t ws_size,
                              hipStream_t stream)
{
    const float* x     = (const float*)d_in[0];
    const int*   ei    = (const int*)d_in[1];
    const int*   batch = (const int*)d_in[2];
    const float* w1    = (const float*)d_in[3];
    const float* b1    = (const float*)d_in[4];
    const float* w2    = (const float*)d_in[5];
    const float* b2    = (const float*)d_in[6];
    const float* gamma = (const float*)d_in[7];
    const float* beta  = (const float*)d_in[8];
    const float* lin_w = (const float*)d_in[9];
    const float* lin_b = (const float*)d_in[10];
    const float* fin_w = (const float*)d_in[11];
    const float* fin_b = (const float*)d_in[12];
    float* out = (float*)d_out;

    const int N = in_sizes[0] / 64;
    const int E = in_sizes[1] / 2;
    const int L = in_sizes[3] / 4096;
    const int G = out_size / 10;
    const float invN = 1.0f / (float)N;
    const int NB = (N + NPB - 1) / NPB;   // buckets (<=512 for N<=131072)

    char* ws = (char*)d_ws;
    size_t off = 0;
    auto alloc = [&](size_t bytes) -> void* {
        void* p = ws + off;
        off += (bytes + 255) & ~(size_t)255;
        return p;
    };
    unsigned short* xbf = (unsigned short*)alloc((size_t)N * 64 * 2);
    unsigned short* z0  = (unsigned short*)alloc((size_t)N * 64 * 2);
    unsigned short* z1  = (unsigned short*)alloc((size_t)N * 64 * 2);
    float* aggbuf  = (float*)alloc((size_t)N * 64 * 4);
    float* xp      = (float*)alloc((size_t)G * 192 * 4);
    float* xpz     = (float*)alloc((size_t)G * 64 * 4);
    float* bnstats = (float*)alloc((size_t)L * 128 * 4);
    float* scsh    = (float*)alloc(128 * 4);
    int*   cnt      = (int*)alloc((size_t)G * 4);
    int*   deg      = (int*)alloc((size_t)N * 4);
    int*   rowstart = (int*)alloc((size_t)N * 4);
    int*   eidx     = (int*)alloc((size_t)E * 4);
    unsigned* part  = (unsigned*)alloc((size_t)E * 4);
    int*   bucketCnt    = (int*)alloc((size_t)NB * 4);
    int*   bucketStart  = (int*)alloc((size_t)(NB + 1) * 4);
    int*   bucketCursor = (int*)alloc((size_t)NB * 4);

    const int* srcIdx = ei;
    const int* dstIdx = ei + E;

    // ---- setup: bucketed CSR + counts + x->bf16 ----
    hipMemsetAsync(bucketCnt, 0, (size_t)NB * 4, stream);
    hipMemsetAsync(bnstats, 0, (size_t)L * 128 * 4, stream);
    hipMemsetAsync(xpz, 0, (size_t)G * 64 * 4, stream);
    hipMemsetAsync(cnt, 0, (size_t)G * 4, stream);
    bh_kernel<<<(E + BH_EPB - 1) / BH_EPB, 256, 0, stream>>>(dstIdx, bucketCnt, E, NB);
    bscan_kernel<<<1, 512, 0, stream>>>(bucketCnt, bucketStart, bucketCursor, NB);
    part_kernel<<<(E + PT_EPB - 1) / PT_EPB, 256, 0, stream>>>(
        srcIdx, dstIdx, bucketCursor, part, E, NB);
    bcsr_kernel<<<NB, 256, 0, stream>>>(part, bucketStart, deg, rowstart, eidx, N);
    cnt_kernel<<<(N + 255) / 256, 256, 0, stream>>>(batch, cnt, N);
    xbf_kernel<<<(N * 16 + 255) / 256, 256, 0, stream>>>(x, xbf, N * 16);

    const int nAggBlk = (N + 3) / 4;
    const int nMlpBlk = (N + TN - 1) / TN;
    unsigned short* zprev = xbf;
    unsigned short* zcur = z0;
    for (int l = 0; l < L; ++l) {
        agg_kernel<<<nAggBlk, 256, 0, stream>>>(
            zprev, (l == 0) ? nullptr : scsh,
            rowstart, deg, eidx, aggbuf, N);
        mlp_kernel<<<nMlpBlk, 256, 0, stream>>>(
            aggbuf, batch, w1, b1, w2, b2,
            zcur, bnstats + (size_t)l * 128, xpz, l, N);
        finalize_kernel<<<(G * 64 + 255) / 256, 256, 0, stream>>>(
            xp, bnstats + (size_t)l * 128, gamma, beta, cnt, xpz, scsh, l, G, invN);
        zprev = zcur;
        zcur = (zcur == z0) ? z1 : z0;
    }
    final_kernel<<<(G * 64 + 255) / 256, 256, 0, stream>>>(xp, lin_w, lin_b,
                                                           fin_w, fin_b, out, G);
}

// Round 6
// 379.851 us; speedup vs baseline: 2.5973x; 1.1947x over previous
//
#include <hip/hip_runtime.h>

#define BN_EPS 1e-5f
#define TN 128        // nodes per MLP block
#define NPB 256       // nodes per bucket
#define BCAP 8192     // LDS edge cap per bucket (avg 4096)
#define BH_EPB 8192   // edges per block, histogram
#define PT_EPB 4096   // edges per block, partition

static __device__ __forceinline__ unsigned short f2bf(float f) {
    unsigned u = __float_as_uint(f);
    u += 0x7fff + ((u >> 16) & 1);
    return (unsigned short)(u >> 16);
}
static __device__ __forceinline__ float bf2f(unsigned short s) {
    return __uint_as_float(((unsigned)s) << 16);
}

// ============ x -> bf16 ============
__global__ __launch_bounds__(256) void xbf_kernel(
    const float* __restrict__ x, unsigned short* __restrict__ xbf, int n4)
{
    const int i = blockIdx.x * 256 + threadIdx.x;
    if (i < n4) {
        const float4 v = reinterpret_cast<const float4*>(x)[i];
        ushort4 o;
        o.x = f2bf(v.x); o.y = f2bf(v.y); o.z = f2bf(v.z); o.w = f2bf(v.w);
        reinterpret_cast<ushort4*>(xbf)[i] = o;
    }
}

// ============ bucket histogram: bucketCnt[dst>>8]++ ============
__global__ __launch_bounds__(256) void bh_kernel(
    const int* __restrict__ dst, int* __restrict__ bucketCnt, int E, int NB)
{
    __shared__ int lh[512];
    const int tid = threadIdx.x;
    for (int i = tid; i < NB; i += 256) lh[i] = 0;
    __syncthreads();
    const int base = blockIdx.x * BH_EPB;
#pragma unroll
    for (int k = 0; k < BH_EPB / 256; ++k) {
        const int e = base + k * 256 + tid;
        if (e < E) atomicAdd(&lh[dst[e] >> 8], 1);
    }
    __syncthreads();
    for (int i = tid; i < NB; i += 256) {
        const int c = lh[i];
        if (c > 0) atomicAdd(&bucketCnt[i], c);
    }
}

// ============ bucket scan (1 block, 512 thr; NB <= 512) ============
__global__ __launch_bounds__(512) void bscan_kernel(
    const int* __restrict__ bucketCnt, int* __restrict__ bucketStart,
    int* __restrict__ bucketCursor, int NB)
{
    __shared__ int ls[512];
    const int t = threadIdx.x;
    const int v = (t < NB) ? bucketCnt[t] : 0;
    ls[t] = v;
    __syncthreads();
    for (int off = 1; off < 512; off <<= 1) {
        const int a = ls[t];
        const int b = (t >= off) ? ls[t - off] : 0;
        __syncthreads();
        ls[t] = a + b;
        __syncthreads();
    }
    const int excl = ls[t] - v;
    if (t < NB) { bucketStart[t] = excl; bucketCursor[t] = excl; }
    if (t == 511) bucketStart[NB] = ls[511];
}

// ============ partition: part[] = (src<<8)|dstloc, bucket-contiguous ============
__global__ __launch_bounds__(256) void part_kernel(
    const int* __restrict__ src, const int* __restrict__ dst,
    int* __restrict__ bucketCursor, unsigned* __restrict__ part, int E, int NB)
{
    __shared__ int lh[512];
    __shared__ int lbase[512];
    const int tid = threadIdx.x;
    const int base = blockIdx.x * PT_EPB;
    for (int i = tid; i < NB; i += 256) lh[i] = 0;
    __syncthreads();
#pragma unroll
    for (int k = 0; k < PT_EPB / 256; ++k) {
        const int e = base + k * 256 + tid;
        if (e < E) atomicAdd(&lh[dst[e] >> 8], 1);
    }
    __syncthreads();
    for (int i = tid; i < NB; i += 256) {
        const int c = lh[i];
        lbase[i] = (c > 0) ? atomicAdd(&bucketCursor[i], c) : 0;
        lh[i] = 0;  // reuse as local cursor
    }
    __syncthreads();
#pragma unroll
    for (int k = 0; k < PT_EPB / 256; ++k) {
        const int e = base + k * 256 + tid;
        if (e < E) {
            const int d = dst[e];
            const int b = d >> 8;
            const int off = atomicAdd(&lh[b], 1);
            part[lbase[b] + off] = ((unsigned)src[e] << 8) | (unsigned)(d & 255);
        }
    }
}

// ============ per-bucket CSR build: deg/rowstart/eidx ============
__global__ __launch_bounds__(256) void bcsr_kernel(
    const unsigned* __restrict__ part, const int* __restrict__ bucketStart,
    int* __restrict__ deg, int* __restrict__ rowstart,
    int* __restrict__ eidx, int nN)
{
    __shared__ unsigned sSrc[BCAP];
    __shared__ int ldeg[256], ls[256], lcur[256];
    const int b = blockIdx.x;
    const int tid = threadIdx.x;
    const int sStart = bucketStart[b];
    const int cnt = bucketStart[b + 1] - sStart;
    const bool ldsok = (cnt <= BCAP);

    ldeg[tid] = 0;
    __syncthreads();
    for (int i = tid; i < cnt; i += 256) {
        const unsigned v = part[sStart + i];
        if (ldsok) sSrc[i] = v;
        atomicAdd(&ldeg[v & 255u], 1);
    }
    __syncthreads();
    // exclusive scan of ldeg
    const int dv = ldeg[tid];
    ls[tid] = dv;
    __syncthreads();
    for (int off = 1; off < 256; off <<= 1) {
        const int a = ls[tid];
        const int c = (tid >= off) ? ls[tid - off] : 0;
        __syncthreads();
        ls[tid] = a + c;
        __syncthreads();
    }
    const int excl = ls[tid] - dv;
    lcur[tid] = excl;
    const int node = b * NPB + tid;
    if (node < nN) {
        deg[node] = dv;
        rowstart[node] = sStart + excl;
    }
    __syncthreads();
    for (int i = tid; i < cnt; i += 256) {
        const unsigned v = ldsok ? sSrc[i] : part[sStart + i];
        const int dloc = (int)(v & 255u);
        const int p = atomicAdd(&lcur[dloc], 1);
        eidx[sStart + p] = (int)(v >> 8);
    }
}

// ============ graph sizes from sorted batch: boundary detection ============
// cnt[g] = (index after last occurrence) - (index of first occurrence); 2 atomics/graph.
__global__ __launch_bounds__(256) void cnt_kernel(
    const int* __restrict__ batch, int* __restrict__ cnt, int nN)
{
    const int n = blockIdx.x * 256 + threadIdx.x;
    if (n >= nN) return;
    const int g = batch[n];
    const bool firstb = (n == 0) || (batch[n - 1] != g);
    const bool lastb  = (n == nN - 1) || (batch[n + 1] != g);
    if (lastb)  atomicAdd(&cnt[g], n + 1);
    if (firstb) atomicAdd(&cnt[g], -n);
}

// ============ aggregation: agg[n] = sc*(z[n] + sum_in z[s]) + (deg+1)*sh ============
// 1 node/wave; quarter-wave (16 lanes x ushort4 = 128B) per edge; 4 edges in flight.
__global__ __launch_bounds__(256) void agg_kernel(
    const unsigned short* __restrict__ z, const float* __restrict__ scsh,
    const int* __restrict__ rowstart, const int* __restrict__ deg,
    const int* __restrict__ eidx, float* __restrict__ agg, int nN)
{
    const int node = blockIdx.x * 4 + (threadIdx.x >> 6);
    if (node >= nN) return;
    const int lane = threadIdx.x & 63;
    const int q = lane >> 4;          // edge slot within group of 4
    const int fr = (lane & 15) * 4;   // feature quad
    const int rs = rowstart[node];
    const int d = deg[node];

    float a0 = 0.f, a1 = 0.f, a2 = 0.f, a3 = 0.f;
    if (q == 0) {
        const ushort4 v = *reinterpret_cast<const ushort4*>(z + (size_t)node * 64 + fr);
        a0 = bf2f(v.x); a1 = bf2f(v.y); a2 = bf2f(v.z); a3 = bf2f(v.w);
    }
    for (int i = 0; i < d; i += 16) {
        const int j0 = i + q, j1 = j0 + 4, j2 = j0 + 8, j3 = j0 + 12;
        const int c0 = min(j0, d - 1), c1 = min(j1, d - 1);
        const int c2 = min(j2, d - 1), c3 = min(j3, d - 1);
        const int s0 = eidx[rs + c0], s1 = eidx[rs + c1];
        const int s2 = eidx[rs + c2], s3 = eidx[rs + c3];
        const ushort4 v0 = *reinterpret_cast<const ushort4*>(z + (size_t)s0 * 64 + fr);
        const ushort4 v1 = *reinterpret_cast<const ushort4*>(z + (size_t)s1 * 64 + fr);
        const ushort4 v2 = *reinterpret_cast<const ushort4*>(z + (size_t)s2 * 64 + fr);
        const ushort4 v3 = *reinterpret_cast<const ushort4*>(z + (size_t)s3 * 64 + fr);
        const float w0 = (j0 < d) ? 1.f : 0.f;
        const float w1 = (j1 < d) ? 1.f : 0.f;
        const float w2 = (j2 < d) ? 1.f : 0.f;
        const float w3 = (j3 < d) ? 1.f : 0.f;
        a0 = fmaf(w0, bf2f(v0.x), a0); a1 = fmaf(w0, bf2f(v0.y), a1);
        a2 = fmaf(w0, bf2f(v0.z), a2); a3 = fmaf(w0, bf2f(v0.w), a3);
        a0 = fmaf(w1, bf2f(v1.x), a0); a1 = fmaf(w1, bf2f(v1.y), a1);
        a2 = fmaf(w1, bf2f(v1.z), a2); a3 = fmaf(w1, bf2f(v1.w), a3);
        a0 = fmaf(w2, bf2f(v2.x), a0); a1 = fmaf(w2, bf2f(v2.y), a1);
        a2 = fmaf(w2, bf2f(v2.z), a2); a3 = fmaf(w2, bf2f(v2.w), a3);
        a0 = fmaf(w3, bf2f(v3.x), a0); a1 = fmaf(w3, bf2f(v3.y), a1);
        a2 = fmaf(w3, bf2f(v3.z), a2); a3 = fmaf(w3, bf2f(v3.w), a3);
    }
    a0 += __shfl_xor(a0, 16); a0 += __shfl_xor(a0, 32);
    a1 += __shfl_xor(a1, 16); a1 += __shfl_xor(a1, 32);
    a2 += __shfl_xor(a2, 16); a2 += __shfl_xor(a2, 32);
    a3 += __shfl_xor(a3, 16); a3 += __shfl_xor(a3, 32);
    if (lane < 16) {
        float4 sc = make_float4(1.f, 1.f, 1.f, 1.f);
        float4 sh = make_float4(0.f, 0.f, 0.f, 0.f);
        if (scsh) {
            sc = *reinterpret_cast<const float4*>(scsh + fr);
            sh = *reinterpret_cast<const float4*>(scsh + 64 + fr);
        }
        const float c = (float)(d + 1);
        float4 o;
        o.x = fmaf(a0, sc.x, c * sh.x);
        o.y = fmaf(a1, sc.y, c * sh.y);
        o.z = fmaf(a2, sc.z, c * sh.z);
        o.w = fmaf(a3, sc.w, c * sh.w);
        *reinterpret_cast<float4*>(agg + (size_t)node * 64 + fr) = o;
    }
}

// ============ fused MLP: z = relu(relu(agg@W1+b1)@W2+b2) -> bf16, + BN stats + pool(z) ====
__global__ __launch_bounds__(256) void mlp_kernel(
    const float* __restrict__ agg, const int* __restrict__ batch,
    const float* __restrict__ w1, const float* __restrict__ b1,
    const float* __restrict__ w2, const float* __restrict__ b2,
    unsigned short* __restrict__ zout, float* __restrict__ bnstats,
    float* __restrict__ xpz, int layer, int nN)
{
    __shared__ float sA[64 * 132];
    __shared__ float sW[64 * 64];
    __shared__ float sB1[64], sB2[64], sSum[64], sSq[64];
    __shared__ float sPool[4 * 64];
    __shared__ int sGfirst;
    const int tid = threadIdx.x;
    const int n0 = blockIdx.x * TN;

    const float4* w1v = reinterpret_cast<const float4*>(w1 + (size_t)layer * 4096);
    float4* sWv = reinterpret_cast<float4*>(sW);
    for (int i = tid; i < 1024; i += 256) sWv[i] = w1v[i];
    if (tid < 64) {
        sB1[tid] = b1[layer * 64 + tid];
        sB2[tid] = b2[layer * 64 + tid];
        sSum[tid] = 0.f; sSq[tid] = 0.f;
    }
    sPool[tid] = 0.f;
    if (tid == 0) sGfirst = batch[n0];

    for (int i = tid; i < TN * 16; i += 256) {
        const int n = i >> 4;
        const int k4 = i & 15;
        const int node = n0 + n;
        float4 v = make_float4(0.f, 0.f, 0.f, 0.f);
        if (node < nN)
            v = *reinterpret_cast<const float4*>(agg + (size_t)node * 64 + k4 * 4);
        const int k = k4 * 4;
        sA[(k + 0) * 132 + n] = v.x;
        sA[(k + 1) * 132 + n] = v.y;
        sA[(k + 2) * 132 + n] = v.z;
        sA[(k + 3) * 132 + n] = v.w;
    }
    __syncthreads();

    const int jq = tid & 15;
    const int no = tid >> 4;
    float acc[8][4];

#pragma unroll
    for (int nn = 0; nn < 8; ++nn)
#pragma unroll
        for (int jj = 0; jj < 4; ++jj) acc[nn][jj] = sB1[jq * 4 + jj];
#pragma unroll 4
    for (int k = 0; k < 64; ++k) {
        const float4 a0 = *reinterpret_cast<const float4*>(&sA[k * 132 + no * 8]);
        const float4 a1 = *reinterpret_cast<const float4*>(&sA[k * 132 + no * 8 + 4]);
        const float4 wv4 = *reinterpret_cast<const float4*>(&sW[k * 64 + jq * 4]);
        const float av[8] = {a0.x, a0.y, a0.z, a0.w, a1.x, a1.y, a1.z, a1.w};
        const float wj[4] = {wv4.x, wv4.y, wv4.z, wv4.w};
#pragma unroll
        for (int nn = 0; nn < 8; ++nn)
#pragma unroll
            for (int jj = 0; jj < 4; ++jj) acc[nn][jj] = fmaf(av[nn], wj[jj], acc[nn][jj]);
    }
    __syncthreads();

#pragma unroll
    for (int nn = 0; nn < 8; ++nn)
#pragma unroll
        for (int jj = 0; jj < 4; ++jj)
            sA[(jq * 4 + jj) * 132 + no * 8 + nn] = fmaxf(acc[nn][jj], 0.f);
    const float4* w2v = reinterpret_cast<const float4*>(w2 + (size_t)layer * 4096);
    for (int i = tid; i < 1024; i += 256) sWv[i] = w2v[i];
    __syncthreads();

#pragma unroll
    for (int nn = 0; nn < 8; ++nn)
#pragma unroll
        for (int jj = 0; jj < 4; ++jj) acc[nn][jj] = sB2[jq * 4 + jj];
#pragma unroll 4
    for (int k = 0; k < 64; ++k) {
        const float4 a0 = *reinterpret_cast<const float4*>(&sA[k * 132 + no * 8]);
        const float4 a1 = *reinterpret_cast<const float4*>(&sA[k * 132 + no * 8 + 4]);
        const float4 wv4 = *reinterpret_cast<const float4*>(&sW[k * 64 + jq * 4]);
        const float av[8] = {a0.x, a0.y, a0.z, a0.w, a1.x, a1.y, a1.z, a1.w};
        const float wj[4] = {wv4.x, wv4.y, wv4.z, wv4.w};
#pragma unroll
        for (int nn = 0; nn < 8; ++nn)
#pragma unroll
            for (int jj = 0; jj < 4; ++jj) acc[nn][jj] = fmaf(av[nn], wj[jj], acc[nn][jj]);
    }

#pragma unroll
    for (int nn = 0; nn < 8; ++nn) {
        const int node = n0 + no * 8 + nn;
#pragma unroll
        for (int jj = 0; jj < 4; ++jj) acc[nn][jj] = fmaxf(acc[nn][jj], 0.f);
        if (node < nN) {
            ushort4 o;
            o.x = f2bf(acc[nn][0]); o.y = f2bf(acc[nn][1]);
            o.z = f2bf(acc[nn][2]); o.w = f2bf(acc[nn][3]);
            *reinterpret_cast<ushort4*>(zout + (size_t)node * 64 + jq * 4) = o;
        }
    }
#pragma unroll
    for (int jj = 0; jj < 4; ++jj) {
        float s = 0.f, qq = 0.f;
#pragma unroll
        for (int nn = 0; nn < 8; ++nn) {
            const int node = n0 + no * 8 + nn;
            if (node < nN) { const float v = acc[nn][jj]; s += v; qq += v * v; }
        }
        atomicAdd(&sSum[jq * 4 + jj], s);
        atomicAdd(&sSq[jq * 4 + jj], qq);
    }
    {
        int curg = -1;
        float ps[4] = {0.f, 0.f, 0.f, 0.f};
        const int gfirst = sGfirst;
#pragma unroll
        for (int nn = 0; nn < 8; ++nn) {
            const int node = n0 + no * 8 + nn;
            if (node < nN) {
                const int g = batch[node];
                if (g != curg) {
                    if (curg >= 0) {
                        const int lg = curg - gfirst;
                        if (lg < 4) {
#pragma unroll
                            for (int jj = 0; jj < 4; ++jj)
                                atomicAdd(&sPool[lg * 64 + jq * 4 + jj], ps[jj]);
                        } else {
#pragma unroll
                            for (int jj = 0; jj < 4; ++jj)
                                atomicAdd(&xpz[(size_t)curg * 64 + jq * 4 + jj], ps[jj]);
                        }
                    }
                    curg = g;
                    ps[0] = ps[1] = ps[2] = ps[3] = 0.f;
                }
#pragma unroll
                for (int jj = 0; jj < 4; ++jj) ps[jj] += acc[nn][jj];
            }
        }
        if (curg >= 0) {
            const int lg = curg - gfirst;
            if (lg < 4) {
#pragma unroll
                for (int jj = 0; jj < 4; ++jj)
                    atomicAdd(&sPool[lg * 64 + jq * 4 + jj], ps[jj]);
            } else {
#pragma unroll
                for (int jj = 0; jj < 4; ++jj)
                    atomicAdd(&xpz[(size_t)curg * 64 + jq * 4 + jj], ps[jj]);
            }
        }
    }
    __syncthreads();
    {
        const int lg = tid >> 6, d = tid & 63;
        const float v = sPool[tid];
        if (v != 0.f) atomicAdd(&xpz[(size_t)(sGfirst + lg) * 64 + d], v);
    }
    if (tid < 64) {
        atomicAdd(&bnstats[tid], sSum[tid]);
        atomicAdd(&bnstats[64 + tid], sSq[tid]);
    }
}

// ============ finalize: xp = sc*xpz + cnt*sh ; emit scsh for next layer; zero xpz ====
__global__ __launch_bounds__(256) void finalize_kernel(
    float* __restrict__ xp, const float* __restrict__ bnstats,
    const float* __restrict__ gamma, const float* __restrict__ beta,
    const int* __restrict__ cnt, float* __restrict__ xpz,
    float* __restrict__ scsh, int layer, int nG, float invN)
{
    const int i = blockIdx.x * 256 + threadIdx.x;
    if (i >= nG * 64) return;
    const int g = i >> 6, d = i & 63;
    const float mean = bnstats[d] * invN;
    const float var  = fmaxf(bnstats[64 + d] * invN - mean * mean, 0.f);
    const float sc = gamma[layer * 64 + d] * rsqrtf(var + BN_EPS);
    const float sh = beta[layer * 64 + d] - mean * sc;
    if (g == 0) { scsh[d] = sc; scsh[64 + d] = sh; }
    xp[(size_t)g * 192 + layer * 64 + d] = fmaf(sc, xpz[i], (float)cnt[g] * sh);
    xpz[i] = 0.f;
}

// ============ head ============
__global__ __launch_bounds__(256) void final_kernel(
    const float* __restrict__ xp, const float* __restrict__ lin_w,
    const float* __restrict__ lin_b, const float* __restrict__ fin_w,
    const float* __restrict__ fin_b, float* __restrict__ out, int nG)
{
    const int g = (blockIdx.x * 256 + threadIdx.x) >> 6;
    const int lane = threadIdx.x & 63;
    if (g >= nG) return;
    const float* xr = xp + (size_t)g * 192;
    float acc = lin_b[lane];
    for (int k = 0; k < 192; ++k) acc = fmaf(xr[k], lin_w[k * 64 + lane], acc);
    const float t = fmaxf(acc, 0.f);
    float o[10];
#pragma unroll
    for (int c = 0; c < 10; ++c) {
        float p = t * fin_w[lane * 10 + c];
#pragma unroll
        for (int off = 32; off > 0; off >>= 1) p += __shfl_xor(p, off);
        o[c] = p + fin_b[c];
    }
    float m = o[0];
#pragma unroll
    for (int c = 1; c < 10; ++c) m = fmaxf(m, o[c]);
    float Z = 0.f;
#pragma unroll
    for (int c = 0; c < 10; ++c) Z += expf(o[c] - m);
    const float lz = m + logf(Z);
#pragma unroll
    for (int c = 0; c < 10; ++c)
        if (lane == c) out[(size_t)g * 10 + c] = o[c] - lz;
}

extern "C" void kernel_launch(void* const* d_in, const int* in_sizes, int n_in,
                              void* d_out, int out_size, void* d_ws, size_t ws_size,
                              hipStream_t stream)
{
    const float* x     = (const float*)d_in[0];
    const int*   ei    = (const int*)d_in[1];
    const int*   batch = (const int*)d_in[2];
    const float* w1    = (const float*)d_in[3];
    const float* b1    = (const float*)d_in[4];
    const float* w2    = (const float*)d_in[5];
    const float* b2    = (const float*)d_in[6];
    const float* gamma = (const float*)d_in[7];
    const float* beta  = (const float*)d_in[8];
    const float* lin_w = (const float*)d_in[9];
    const float* lin_b = (const float*)d_in[10];
    const float* fin_w = (const float*)d_in[11];
    const float* fin_b = (const float*)d_in[12];
    float* out = (float*)d_out;

    const int N = in_sizes[0] / 64;
    const int E = in_sizes[1] / 2;
    const int L = in_sizes[3] / 4096;
    const int G = out_size / 10;
    const float invN = 1.0f / (float)N;
    const int NB = (N + NPB - 1) / NPB;   // buckets (<=512 for N<=131072)

    char* ws = (char*)d_ws;
    size_t off = 0;
    auto alloc = [&](size_t bytes) -> void* {
        void* p = ws + off;
        off += (bytes + 255) & ~(size_t)255;
        return p;
    };
    unsigned short* xbf = (unsigned short*)alloc((size_t)N * 64 * 2);
    unsigned short* z0  = (unsigned short*)alloc((size_t)N * 64 * 2);
    unsigned short* z1  = (unsigned short*)alloc((size_t)N * 64 * 2);
    float* aggbuf  = (float*)alloc((size_t)N * 64 * 4);
    float* xp      = (float*)alloc((size_t)G * 192 * 4);
    float* xpz     = (float*)alloc((size_t)G * 64 * 4);
    float* bnstats = (float*)alloc((size_t)L * 128 * 4);
    float* scsh    = (float*)alloc(128 * 4);
    int*   cnt      = (int*)alloc((size_t)G * 4);
    int*   deg      = (int*)alloc((size_t)N * 4);
    int*   rowstart = (int*)alloc((size_t)N * 4);
    int*   eidx     = (int*)alloc((size_t)E * 4);
    unsigned* part  = (unsigned*)alloc((size_t)E * 4);
    int*   bucketCnt    = (int*)alloc((size_t)NB * 4);
    int*   bucketStart  = (int*)alloc((size_t)(NB + 1) * 4);
    int*   bucketCursor = (int*)alloc((size_t)NB * 4);

    const int* srcIdx = ei;
    const int* dstIdx = ei + E;

    // ---- setup: bucketed CSR + counts + x->bf16 ----
    hipMemsetAsync(bucketCnt, 0, (size_t)NB * 4, stream);
    hipMemsetAsync(bnstats, 0, (size_t)L * 128 * 4, stream);
    hipMemsetAsync(xpz, 0, (size_t)G * 64 * 4, stream);
    hipMemsetAsync(cnt, 0, (size_t)G * 4, stream);
    bh_kernel<<<(E + BH_EPB - 1) / BH_EPB, 256, 0, stream>>>(dstIdx, bucketCnt, E, NB);
    bscan_kernel<<<1, 512, 0, stream>>>(bucketCnt, bucketStart, bucketCursor, NB);
    part_kernel<<<(E + PT_EPB - 1) / PT_EPB, 256, 0, stream>>>(
        srcIdx, dstIdx, bucketCursor, part, E, NB);
    bcsr_kernel<<<NB, 256, 0, stream>>>(part, bucketStart, deg, rowstart, eidx, N);
    cnt_kernel<<<(N + 255) / 256, 256, 0, stream>>>(batch, cnt, N);
    xbf_kernel<<<(N * 16 + 255) / 256, 256, 0, stream>>>(x, xbf, N * 16);

    const int nAggBlk = (N + 3) / 4;
    const int nMlpBlk = (N + TN - 1) / TN;
    unsigned short* zprev = xbf;
    unsigned short* zcur = z0;
    for (int l = 0; l < L; ++l) {
        agg_kernel<<<nAggBlk, 256, 0, stream>>>(
            zprev, (l == 0) ? nullptr : scsh,
            rowstart, deg, eidx, aggbuf, N);
        mlp_kernel<<<nMlpBlk, 256, 0, stream>>>(
            aggbuf, batch, w1, b1, w2, b2,
            zcur, bnstats + (size_t)l * 128, xpz, l, N);
        finalize_kernel<<<(G * 64 + 255) / 256, 256, 0, stream>>>(
            xp, bnstats + (size_t)l * 128, gamma, beta, cnt, xpz, scsh, l, G, invN);
        zprev = zcur;
        zcur = (zcur == z0) ? z1 : z0;
    }
    final_kernel<<<(G * 64 + 255) / 256, 256, 0, stream>>>(xp, lin_w, lin_b,
                                                           fin_w, fin_b, out, G);
}

// Round 8
// 333.003 us; speedup vs baseline: 2.9627x; 1.1407x over previous
//
#include <hip/hip_runtime.h>

#define BN_EPS 1e-5f
#define TN 128        // nodes per MLP block
#define NPB 256       // nodes per bucket
#define BCAP 8192     // LDS edge cap per bucket (avg 4096)
#define BH_EPB 8192   // edges per block, histogram
#define PT_EPB 4096   // edges per block, partition

typedef __attribute__((ext_vector_type(8))) short bf16x8;
typedef __attribute__((ext_vector_type(4))) float f32x4;

static __device__ __forceinline__ unsigned short f2bf(float f) {
    unsigned u = __float_as_uint(f);
    u += 0x7fff + ((u >> 16) & 1);
    return (unsigned short)(u >> 16);
}
static __device__ __forceinline__ float bf2f(unsigned short s) {
    return __uint_as_float(((unsigned)s) << 16);
}

// ============ x -> bf16 ============
__global__ __launch_bounds__(256) void xbf_kernel(
    const float* __restrict__ x, unsigned short* __restrict__ xbf, int n4)
{
    const int i = blockIdx.x * 256 + threadIdx.x;
    if (i < n4) {
        const float4 v = reinterpret_cast<const float4*>(x)[i];
        ushort4 o;
        o.x = f2bf(v.x); o.y = f2bf(v.y); o.z = f2bf(v.z); o.w = f2bf(v.w);
        reinterpret_cast<ushort4*>(xbf)[i] = o;
    }
}

// ============ bucket histogram ============
__global__ __launch_bounds__(256) void bh_kernel(
    const int* __restrict__ dst, int* __restrict__ bucketCnt, int E, int NB)
{
    __shared__ int lh[512];
    const int tid = threadIdx.x;
    for (int i = tid; i < NB; i += 256) lh[i] = 0;
    __syncthreads();
    const int base = blockIdx.x * BH_EPB;
#pragma unroll
    for (int k = 0; k < BH_EPB / 256; ++k) {
        const int e = base + k * 256 + tid;
        if (e < E) atomicAdd(&lh[dst[e] >> 8], 1);
    }
    __syncthreads();
    for (int i = tid; i < NB; i += 256) {
        const int c = lh[i];
        if (c > 0) atomicAdd(&bucketCnt[i], c);
    }
}

// ============ bucket scan ============
__global__ __launch_bounds__(512) void bscan_kernel(
    const int* __restrict__ bucketCnt, int* __restrict__ bucketStart,
    int* __restrict__ bucketCursor, int NB)
{
    __shared__ int ls[512];
    const int t = threadIdx.x;
    const int v = (t < NB) ? bucketCnt[t] : 0;
    ls[t] = v;
    __syncthreads();
    for (int off = 1; off < 512; off <<= 1) {
        const int a = ls[t];
        const int b = (t >= off) ? ls[t - off] : 0;
        __syncthreads();
        ls[t] = a + b;
        __syncthreads();
    }
    const int excl = ls[t] - v;
    if (t < NB) { bucketStart[t] = excl; bucketCursor[t] = excl; }
    if (t == 511) bucketStart[NB] = ls[511];
}

// ============ partition ============
__global__ __launch_bounds__(256) void part_kernel(
    const int* __restrict__ src, const int* __restrict__ dst,
    int* __restrict__ bucketCursor, unsigned* __restrict__ part, int E, int NB)
{
    __shared__ int lh[512];
    __shared__ int lbase[512];
    const int tid = threadIdx.x;
    const int base = blockIdx.x * PT_EPB;
    for (int i = tid; i < NB; i += 256) lh[i] = 0;
    __syncthreads();
#pragma unroll
    for (int k = 0; k < PT_EPB / 256; ++k) {
        const int e = base + k * 256 + tid;
        if (e < E) atomicAdd(&lh[dst[e] >> 8], 1);
    }
    __syncthreads();
    for (int i = tid; i < NB; i += 256) {
        const int c = lh[i];
        lbase[i] = (c > 0) ? atomicAdd(&bucketCursor[i], c) : 0;
        lh[i] = 0;
    }
    __syncthreads();
#pragma unroll
    for (int k = 0; k < PT_EPB / 256; ++k) {
        const int e = base + k * 256 + tid;
        if (e < E) {
            const int d = dst[e];
            const int b = d >> 8;
            const int off = atomicAdd(&lh[b], 1);
            part[lbase[b] + off] = ((unsigned)src[e] << 8) | (unsigned)(d & 255);
        }
    }
}

// ============ per-bucket CSR build ============
__global__ __launch_bounds__(256) void bcsr_kernel(
    const unsigned* __restrict__ part, const int* __restrict__ bucketStart,
    int* __restrict__ deg, int* __restrict__ rowstart,
    int* __restrict__ eidx, int nN)
{
    __shared__ unsigned sSrc[BCAP];
    __shared__ int ldeg[256], ls[256], lcur[256];
    const int b = blockIdx.x;
    const int tid = threadIdx.x;
    const int sStart = bucketStart[b];
    const int cnt = bucketStart[b + 1] - sStart;
    const bool ldsok = (cnt <= BCAP);

    ldeg[tid] = 0;
    __syncthreads();
    for (int i = tid; i < cnt; i += 256) {
        const unsigned v = part[sStart + i];
        if (ldsok) sSrc[i] = v;
        atomicAdd(&ldeg[v & 255u], 1);
    }
    __syncthreads();
    const int dv = ldeg[tid];
    ls[tid] = dv;
    __syncthreads();
    for (int off = 1; off < 256; off <<= 1) {
        const int a = ls[tid];
        const int c = (tid >= off) ? ls[tid - off] : 0;
        __syncthreads();
        ls[tid] = a + c;
        __syncthreads();
    }
    const int excl = ls[tid] - dv;
    lcur[tid] = excl;
    const int node = b * NPB + tid;
    if (node < nN) {
        deg[node] = dv;
        rowstart[node] = sStart + excl;
    }
    __syncthreads();
    for (int i = tid; i < cnt; i += 256) {
        const unsigned v = ldsok ? sSrc[i] : part[sStart + i];
        const int dloc = (int)(v & 255u);
        const int p = atomicAdd(&lcur[dloc], 1);
        eidx[sStart + p] = (int)(v >> 8);
    }
}

// ============ graph sizes from sorted batch ============
__global__ __launch_bounds__(256) void cnt_kernel(
    const int* __restrict__ batch, int* __restrict__ cnt, int nN)
{
    const int n = blockIdx.x * 256 + threadIdx.x;
    if (n >= nN) return;
    const int g = batch[n];
    const bool firstb = (n == 0) || (batch[n - 1] != g);
    const bool lastb  = (n == nN - 1) || (batch[n + 1] != g);
    if (lastb)  atomicAdd(&cnt[g], n + 1);
    if (firstb) atomicAdd(&cnt[g], -n);
}

// ============ aggregation: agg[n] = sc*(z[n] + sum_in z[s]) + (deg+1)*sh -> bf16 ====
__global__ __launch_bounds__(256) void agg_kernel(
    const unsigned short* __restrict__ z, const float* __restrict__ scsh,
    const int* __restrict__ rowstart, const int* __restrict__ deg,
    const int* __restrict__ eidx, unsigned short* __restrict__ agg, int nN)
{
    const int node = blockIdx.x * 4 + (threadIdx.x >> 6);
    if (node >= nN) return;
    const int lane = threadIdx.x & 63;
    const int q = lane >> 4;
    const int fr = (lane & 15) * 4;
    const int rs = rowstart[node];
    const int d = deg[node];

    float a0 = 0.f, a1 = 0.f, a2 = 0.f, a3 = 0.f;
    if (q == 0) {
        const ushort4 v = *reinterpret_cast<const ushort4*>(z + (size_t)node * 64 + fr);
        a0 = bf2f(v.x); a1 = bf2f(v.y); a2 = bf2f(v.z); a3 = bf2f(v.w);
    }
    for (int i = 0; i < d; i += 16) {
        const int j0 = i + q, j1 = j0 + 4, j2 = j0 + 8, j3 = j0 + 12;
        const int c0 = min(j0, d - 1), c1 = min(j1, d - 1);
        const int c2 = min(j2, d - 1), c3 = min(j3, d - 1);
        const int s0 = eidx[rs + c0], s1 = eidx[rs + c1];
        const int s2 = eidx[rs + c2], s3 = eidx[rs + c3];
        const ushort4 v0 = *reinterpret_cast<const ushort4*>(z + (size_t)s0 * 64 + fr);
        const ushort4 v1 = *reinterpret_cast<const ushort4*>(z + (size_t)s1 * 64 + fr);
        const ushort4 v2 = *reinterpret_cast<const ushort4*>(z + (size_t)s2 * 64 + fr);
        const ushort4 v3 = *reinterpret_cast<const ushort4*>(z + (size_t)s3 * 64 + fr);
        const float w0 = (j0 < d) ? 1.f : 0.f;
        const float w1 = (j1 < d) ? 1.f : 0.f;
        const float w2 = (j2 < d) ? 1.f : 0.f;
        const float w3 = (j3 < d) ? 1.f : 0.f;
        a0 = fmaf(w0, bf2f(v0.x), a0); a1 = fmaf(w0, bf2f(v0.y), a1);
        a2 = fmaf(w0, bf2f(v0.z), a2); a3 = fmaf(w0, bf2f(v0.w), a3);
        a0 = fmaf(w1, bf2f(v1.x), a0); a1 = fmaf(w1, bf2f(v1.y), a1);
        a2 = fmaf(w1, bf2f(v1.z), a2); a3 = fmaf(w1, bf2f(v1.w), a3);
        a0 = fmaf(w2, bf2f(v2.x), a0); a1 = fmaf(w2, bf2f(v2.y), a1);
        a2 = fmaf(w2, bf2f(v2.z), a2); a3 = fmaf(w2, bf2f(v2.w), a3);
        a0 = fmaf(w3, bf2f(v3.x), a0); a1 = fmaf(w3, bf2f(v3.y), a1);
        a2 = fmaf(w3, bf2f(v3.z), a2); a3 = fmaf(w3, bf2f(v3.w), a3);
    }
    a0 += __shfl_xor(a0, 16); a0 += __shfl_xor(a0, 32);
    a1 += __shfl_xor(a1, 16); a1 += __shfl_xor(a1, 32);
    a2 += __shfl_xor(a2, 16); a2 += __shfl_xor(a2, 32);
    a3 += __shfl_xor(a3, 16); a3 += __shfl_xor(a3, 32);
    if (lane < 16) {
        float4 sc = make_float4(1.f, 1.f, 1.f, 1.f);
        float4 sh = make_float4(0.f, 0.f, 0.f, 0.f);
        if (scsh) {
            sc = *reinterpret_cast<const float4*>(scsh + fr);
            sh = *reinterpret_cast<const float4*>(scsh + 64 + fr);
        }
        const float c = (float)(d + 1);
        ushort4 ob;
        ob.x = f2bf(fmaf(a0, sc.x, c * sh.x));
        ob.y = f2bf(fmaf(a1, sc.y, c * sh.y));
        ob.z = f2bf(fmaf(a2, sc.z, c * sh.z));
        ob.w = f2bf(fmaf(a3, sc.w, c * sh.w));
        *reinterpret_cast<ushort4*>(agg + (size_t)node * 64 + fr) = ob;
    }
}

// ============ MFMA MLP: z = relu(relu(A@W1+b1)@W2+b2) -> bf16, + BN stats + pool ====
// A [128x64] bf16 in LDS (pitch 72); W1t/W2t [64x64] bf16 transposed (pitch 72).
// Wave w owns rows w*32..w*32+31 (2 row-tiles x 4 col-tiles of 16x16, K=64).
// C/D layout (HW-verified m89): col=lane&15, row=(lane>>4)*4+reg.
// A/B k-map (l>>4)*8+i used consistently for both operands -> permutation-invariant.
__global__ __launch_bounds__(256) void mlp_kernel(
    const unsigned short* __restrict__ agg, const int* __restrict__ batch,
    const float* __restrict__ w1, const float* __restrict__ b1,
    const float* __restrict__ w2, const float* __restrict__ b2,
    unsigned short* __restrict__ zout, float* __restrict__ bnstats,
    float* __restrict__ xpz, int layer, int nN)
{
    __shared__ unsigned short sA[128 * 72];
    __shared__ unsigned short sW[2][64 * 72];
    __shared__ float sB[2][64];
    __shared__ float sSum[64], sSq[64];
    __shared__ float sPool[4 * 64];
    __shared__ int sBatch[128];

    const int tid = threadIdx.x;
    const int n0 = blockIdx.x * TN;

    // --- stage A: 2 threads/row, 32 bf16 (4 x uint4) each; zero-pad OOB rows ---
    {
        const int row = tid >> 1;
        const int cg = (tid & 1) * 32;
        const int node = n0 + row;
        uint4 v0 = make_uint4(0, 0, 0, 0), v1 = v0, v2 = v0, v3 = v0;
        if (node < nN) {
            const uint4* g = reinterpret_cast<const uint4*>(agg + (size_t)node * 64 + cg);
            v0 = g[0]; v1 = g[1]; v2 = g[2]; v3 = g[3];
        }
        uint4* dp = reinterpret_cast<uint4*>(&sA[row * 72 + cg]);
        dp[0] = v0; dp[1] = v1; dp[2] = v2; dp[3] = v3;
    }
    // --- stage W1t/W2t (transpose + f32->bf16), biases, batch, stats ---
    {
        const int j = tid & 63;
        const int kb = (tid >> 6) * 16;
        const float* ws1 = w1 + (size_t)layer * 4096;
        const float* ws2 = w2 + (size_t)layer * 4096;
#pragma unroll 4
        for (int i = 0; i < 16; ++i) {
            const int k = kb + i;
            sW[0][j * 72 + k] = f2bf(ws1[k * 64 + j]);
            sW[1][j * 72 + k] = f2bf(ws2[k * 64 + j]);
        }
        if (tid < 64) {
            sB[0][tid] = b1[layer * 64 + tid];
            sB[1][tid] = b2[layer * 64 + tid];
            sSum[tid] = 0.f; sSq[tid] = 0.f;
        }
        if (tid < 128) sBatch[tid] = (n0 + tid < nN) ? batch[n0 + tid] : -1;
        sPool[tid] = 0.f;
    }
    __syncthreads();

    const int w  = tid >> 6;
    const int l  = tid & 63;
    const int lr = l & 15;
    const int hi = l >> 4;

    f32x4 acc[2][4];
    // ---- mm1: T = relu(A @ W1 + b1) ----
#pragma unroll
    for (int rt = 0; rt < 2; ++rt)
#pragma unroll
        for (int ct = 0; ct < 4; ++ct) {
            const float bv = sB[0][ct * 16 + lr];
            acc[rt][ct] = (f32x4){bv, bv, bv, bv};
        }
#pragma unroll
    for (int kb = 0; kb < 2; ++kb) {
        const bf16x8 af0 = *reinterpret_cast<const bf16x8*>(&sA[(w * 32 + lr) * 72 + kb * 32 + hi * 8]);
        const bf16x8 af1 = *reinterpret_cast<const bf16x8*>(&sA[(w * 32 + 16 + lr) * 72 + kb * 32 + hi * 8]);
#pragma unroll
        for (int ct = 0; ct < 4; ++ct) {
            const bf16x8 bfr = *reinterpret_cast<const bf16x8*>(&sW[0][(ct * 16 + lr) * 72 + kb * 32 + hi * 8]);
            acc[0][ct] = __builtin_amdgcn_mfma_f32_16x16x32_bf16(af0, bfr, acc[0][ct], 0, 0, 0);
            acc[1][ct] = __builtin_amdgcn_mfma_f32_16x16x32_bf16(af1, bfr, acc[1][ct], 0, 0, 0);
        }
    }
    __syncthreads();   // done reading A tile
    // write T (relu, bf16) into sA
#pragma unroll
    for (int rt = 0; rt < 2; ++rt)
#pragma unroll
        for (int ct = 0; ct < 4; ++ct)
#pragma unroll
            for (int r = 0; r < 4; ++r)
                sA[(w * 32 + rt * 16 + hi * 4 + r) * 72 + ct * 16 + lr] =
                    f2bf(fmaxf(acc[rt][ct][r], 0.f));
    __syncthreads();

    // ---- mm2: Z = relu(T @ W2 + b2) ----
#pragma unroll
    for (int rt = 0; rt < 2; ++rt)
#pragma unroll
        for (int ct = 0; ct < 4; ++ct) {
            const float bv = sB[1][ct * 16 + lr];
            acc[rt][ct] = (f32x4){bv, bv, bv, bv};
        }
#pragma unroll
    for (int kb = 0; kb < 2; ++kb) {
        const bf16x8 af0 = *reinterpret_cast<const bf16x8*>(&sA[(w * 32 + lr) * 72 + kb * 32 + hi * 8]);
        const bf16x8 af1 = *reinterpret_cast<const bf16x8*>(&sA[(w * 32 + 16 + lr) * 72 + kb * 32 + hi * 8]);
#pragma unroll
        for (int ct = 0; ct < 4; ++ct) {
            const bf16x8 bfr = *reinterpret_cast<const bf16x8*>(&sW[1][(ct * 16 + lr) * 72 + kb * 32 + hi * 8]);
            acc[0][ct] = __builtin_amdgcn_mfma_f32_16x16x32_bf16(af0, bfr, acc[0][ct], 0, 0, 0);
            acc[1][ct] = __builtin_amdgcn_mfma_f32_16x16x32_bf16(af1, bfr, acc[1][ct], 0, 0, 0);
        }
    }

    // ---- epilogue: relu, z store, BN stats, run-length pool ----
    const int gfirst = sBatch[0];
#pragma unroll
    for (int rt = 0; rt < 2; ++rt) {
#pragma unroll
        for (int ct = 0; ct < 4; ++ct) {
            const int j = ct * 16 + lr;
            float s = 0.f, q = 0.f;
            int curg = -1;
            float ps = 0.f;
#pragma unroll
            for (int r = 0; r < 4; ++r) {
                const int lrow = w * 32 + rt * 16 + hi * 4 + r;
                const int node = n0 + lrow;
                const float v = fmaxf(acc[rt][ct][r], 0.f);
                if (node < nN) {
                    zout[(size_t)node * 64 + j] = f2bf(v);
                    s += v; q += v * v;
                    const int g = sBatch[lrow];
                    if (g != curg) {
                        if (curg >= 0) {
                            const int lg = curg - gfirst;
                            if (lg < 4) atomicAdd(&sPool[lg * 64 + j], ps);
                            else        atomicAdd(&xpz[(size_t)curg * 64 + j], ps);
                        }
                        curg = g; ps = 0.f;
                    }
                    ps += v;
                }
            }
            if (curg >= 0) {
                const int lg = curg - gfirst;
                if (lg < 4) atomicAdd(&sPool[lg * 64 + j], ps);
                else        atomicAdd(&xpz[(size_t)curg * 64 + j], ps);
            }
            s += __shfl_xor(s, 16); s += __shfl_xor(s, 32);
            q += __shfl_xor(q, 16); q += __shfl_xor(q, 32);
            if (hi == 0) { atomicAdd(&sSum[j], s); atomicAdd(&sSq[j], q); }
        }
    }
    __syncthreads();
    {
        const int lg = tid >> 6, d = tid & 63;
        const float v = sPool[tid];
        if (v != 0.f) atomicAdd(&xpz[(size_t)(gfirst + lg) * 64 + d], v);
    }
    if (tid < 64) {
        atomicAdd(&bnstats[tid], sSum[tid]);
        atomicAdd(&bnstats[64 + tid], sSq[tid]);
    }
}

// ============ finalize: xp = sc*xpz + cnt*sh ; emit scsh; zero xpz ============
__global__ __launch_bounds__(256) void finalize_kernel(
    float* __restrict__ xp, const float* __restrict__ bnstats,
    const float* __restrict__ gamma, const float* __restrict__ beta,
    const int* __restrict__ cnt, float* __restrict__ xpz,
    float* __restrict__ scsh, int layer, int nG, float invN)
{
    const int i = blockIdx.x * 256 + threadIdx.x;
    if (i >= nG * 64) return;
    const int g = i >> 6, d = i & 63;
    const float mean = bnstats[d] * invN;
    const float var  = fmaxf(bnstats[64 + d] * invN - mean * mean, 0.f);
    const float sc = gamma[layer * 64 + d] * rsqrtf(var + BN_EPS);
    const float sh = beta[layer * 64 + d] - mean * sc;
    if (g == 0) { scsh[d] = sc; scsh[64 + d] = sh; }
    xp[(size_t)g * 192 + layer * 64 + d] = fmaf(sc, xpz[i], (float)cnt[g] * sh);
    xpz[i] = 0.f;
}

// ============ head ============
__global__ __launch_bounds__(256) void final_kernel(
    const float* __restrict__ xp, const float* __restrict__ lin_w,
    const float* __restrict__ lin_b, const float* __restrict__ fin_w,
    const float* __restrict__ fin_b, float* __restrict__ out, int nG)
{
    const int g = (blockIdx.x * 256 + threadIdx.x) >> 6;
    const int lane = threadIdx.x & 63;
    if (g >= nG) return;
    const float* xr = xp + (size_t)g * 192;
    float acc = lin_b[lane];
    for (int k = 0; k < 192; ++k) acc = fmaf(xr[k], lin_w[k * 64 + lane], acc);
    const float t = fmaxf(acc, 0.f);
    float o[10];
#pragma unroll
    for (int c = 0; c < 10; ++c) {
        float p = t * fin_w[lane * 10 + c];
#pragma unroll
        for (int off = 32; off > 0; off >>= 1) p += __shfl_xor(p, off);
        o[c] = p + fin_b[c];
    }
    float m = o[0];
#pragma unroll
    for (int c = 1; c < 10; ++c) m = fmaxf(m, o[c]);
    float Z = 0.f;
#pragma unroll
    for (int c = 0; c < 10; ++c) Z += expf(o[c] - m);
    const float lz = m + logf(Z);
#pragma unroll
    for (int c = 0; c < 10; ++c)
        if (lane == c) out[(size_t)g * 10 + c] = o[c] - lz;
}

extern "C" void kernel_launch(void* const* d_in, const int* in_sizes, int n_in,
                              void* d_out, int out_size, void* d_ws, size_t ws_size,
                              hipStream_t stream)
{
    const float* x     = (const float*)d_in[0];
    const int*   ei    = (const int*)d_in[1];
    const int*   batch = (const int*)d_in[2];
    const float* w1    = (const float*)d_in[3];
    const float* b1    = (const float*)d_in[4];
    const float* w2    = (const float*)d_in[5];
    const float* b2    = (const float*)d_in[6];
    const float* gamma = (const float*)d_in[7];
    const float* beta  = (const float*)d_in[8];
    const float* lin_w = (const float*)d_in[9];
    const float* lin_b = (const float*)d_in[10];
    const float* fin_w = (const float*)d_in[11];
    const float* fin_b = (const float*)d_in[12];
    float* out = (float*)d_out;

    const int N = in_sizes[0] / 64;
    const int E = in_sizes[1] / 2;
    const int L = in_sizes[3] / 4096;
    const int G = out_size / 10;
    const float invN = 1.0f / (float)N;
    const int NB = (N + NPB - 1) / NPB;

    char* ws = (char*)d_ws;
    size_t off = 0;
    auto alloc = [&](size_t bytes) -> void* {
        void* p = ws + off;
        off += (bytes + 255) & ~(size_t)255;
        return p;
    };
    unsigned short* xbf = (unsigned short*)alloc((size_t)N * 64 * 2);
    unsigned short* z0  = (unsigned short*)alloc((size_t)N * 64 * 2);
    unsigned short* z1  = (unsigned short*)alloc((size_t)N * 64 * 2);
    unsigned short* aggbuf = (unsigned short*)alloc((size_t)N * 64 * 2);
    float* xp      = (float*)alloc((size_t)G * 192 * 4);
    float* xpz     = (float*)alloc((size_t)G * 64 * 4);
    float* bnstats = (float*)alloc((size_t)L * 128 * 4);
    float* scsh    = (float*)alloc(128 * 4);
    int*   cnt      = (int*)alloc((size_t)G * 4);
    int*   deg      = (int*)alloc((size_t)N * 4);
    int*   rowstart = (int*)alloc((size_t)N * 4);
    int*   eidx     = (int*)alloc((size_t)E * 4);
    unsigned* part  = (unsigned*)alloc((size_t)E * 4);
    int*   bucketCnt    = (int*)alloc((size_t)NB * 4);
    int*   bucketStart  = (int*)alloc((size_t)(NB + 1) * 4);
    int*   bucketCursor = (int*)alloc((size_t)NB * 4);

    const int* srcIdx = ei;
    const int* dstIdx = ei + E;

    // ---- setup: bucketed CSR + counts + x->bf16 ----
    hipMemsetAsync(bucketCnt, 0, (size_t)NB * 4, stream);
    hipMemsetAsync(bnstats, 0, (size_t)L * 128 * 4, stream);
    hipMemsetAsync(xpz, 0, (size_t)G * 64 * 4, stream);
    hipMemsetAsync(cnt, 0, (size_t)G * 4, stream);
    bh_kernel<<<(E + BH_EPB - 1) / BH_EPB, 256, 0, stream>>>(dstIdx, bucketCnt, E, NB);
    bscan_kernel<<<1, 512, 0, stream>>>(bucketCnt, bucketStart, bucketCursor, NB);
    part_kernel<<<(E + PT_EPB - 1) / PT_EPB, 256, 0, stream>>>(
        srcIdx, dstIdx, bucketCursor, part, E, NB);
    bcsr_kernel<<<NB, 256, 0, stream>>>(part, bucketStart, deg, rowstart, eidx, N);
    cnt_kernel<<<(N + 255) / 256, 256, 0, stream>>>(batch, cnt, N);
    xbf_kernel<<<(N * 16 + 255) / 256, 256, 0, stream>>>(x, xbf, N * 16);

    const int nAggBlk = (N + 3) / 4;
    const int nMlpBlk = (N + TN - 1) / TN;
    unsigned short* zprev = xbf;
    unsigned short* zcur = z0;
    for (int l = 0; l < L; ++l) {
        agg_kernel<<<nAggBlk, 256, 0, stream>>>(
            zprev, (l == 0) ? nullptr : scsh,
            rowstart, deg, eidx, aggbuf, N);
        mlp_kernel<<<nMlpBlk, 256, 0, stream>>>(
            aggbuf, batch, w1, b1, w2, b2,
            zcur, bnstats + (size_t)l * 128, xpz, l, N);
        finalize_kernel<<<(G * 64 + 255) / 256, 256, 0, stream>>>(
            xp, bnstats + (size_t)l * 128, gamma, beta, cnt, xpz, scsh, l, G, invN);
        zprev = zcur;
        zcur = (zcur == z0) ? z1 : z0;
    }
    final_kernel<<<(G * 64 + 255) / 256, 256, 0, stream>>>(xp, lin_w, lin_b,
                                                           fin_w, fin_b, out, G);
}